// Round 3
// baseline (167.910 us; speedup 1.0000x reference)
//
#include <hip/hip_runtime.h>
#include <hip/hip_bf16.h>

// Shapes fixed by the problem:
// B=4, S=1024, D=512, H=64, DK=8, FF=2048, NQ=8. Mtok = B*S = 4096.
// R10: multi-dispatch structure beats persistent mega-kernel.
// R12: bf16 intermediates. R13: wo_lnffn fusion (neutral; kept).
// R14: K-split-2 LDS-staged cores: only -6us — trading prefetch depth for
// waves 1:1 is a wash; LDS ring both caps occupancy AND forces the
// serializing waits.
// R15: qkv/ffnout cores -> NO-LDS direct-fragment GEMM. Operands are
// L2/LLC-resident; each lane loads its MFMA frags (16B short8) straight
// from global into VGPRs (plain tracked loads, compiler-counted vmcnt),
// ping-pong frag double-buffer, 4-wave blocks K-split-4, LDS only for the
// final reduce (48KB) -> 2 blocks/CU, 8 waves/CU (2/SIMD): MFMA of one
// wave overlaps loads of the other.

typedef short short8 __attribute__((ext_vector_type(8)));
typedef float floatx4 __attribute__((ext_vector_type(4)));

#define MFMA_BF16 __builtin_amdgcn_mfma_f32_16x16x32_bf16

__device__ __forceinline__ unsigned short f2bf_bits(float f) {
  __hip_bfloat16 h = __float2bfloat16(f);
  return *reinterpret_cast<unsigned short*>(&h);
}
__device__ __forceinline__ float bfbits2f(unsigned short u) {
  union { unsigned int u; float f; } c;
  c.u = (unsigned int)u << 16;
  return c.f;
}

#define GLOBAL_LOAD_LDS16(g, l)                                               \
  __builtin_amdgcn_global_load_lds(                                           \
      (const __attribute__((address_space(1))) void*)(g),                     \
      (__attribute__((address_space(3))) void*)(l), 16, 0, 0)

// Explicit waits only where global_load_lds (untracked LDS writes) or
// cross-wave LDS hand-off requires them (wo_lnffn + reduces).
#define WAIT_VMCNT0()   asm volatile("s_waitcnt vmcnt(0)" ::: "memory")
#define WAIT_VMCNT8()   asm volatile("s_waitcnt vmcnt(8)" ::: "memory")
#define WAIT_VMCNT10()  asm volatile("s_waitcnt vmcnt(10)" ::: "memory")
#define WAIT_LGKM0()    asm volatile("s_waitcnt lgkmcnt(0)" ::: "memory")
#define BARRIER()       __builtin_amdgcn_s_barrier()
#define CFENCE()        asm volatile("" ::: "memory")

// ---------------------------------------------------------------------------
// Direct-fragment GEMM core (no LDS): acc(64x64) += A[:,kr] @ W[:,kr]^T over
// the wave's K-range. Frag layout for 16x16x32 MFMA: lane = frow + 16*fk;
// af[ks][i] = A[(m0+i*16+frow)][kbeg + t*64 + (ks*4+fk)*8 .. +8].
// Lanes with equal frow, fk=0..3 read one contiguous 64B line per row ->
// 16 lines per load instr; operands are L2-hot so scatter cost is absorbed
// by concurrency. Ping-pong frag buffers, rolled loop bounds liveness.
// ---------------------------------------------------------------------------
__device__ __forceinline__ void frag_load(
    short8 af[2][4], short8 bf[2][4],
    const __hip_bfloat16* const pa[4], const __hip_bfloat16* const pw[4],
    int koff)
{
#pragma unroll
  for (int i = 0; i < 4; ++i) {
    af[0][i] = *(const short8*)(pa[i] + koff);
    af[1][i] = *(const short8*)(pa[i] + koff + 32);
    bf[0][i] = *(const short8*)(pw[i] + koff);
    bf[1][i] = *(const short8*)(pw[i] + koff + 32);
  }
}

__device__ __forceinline__ void mfma_step(
    short8 af[2][4], short8 bf[2][4], floatx4 acc[4][4])
{
#pragma unroll
  for (int ks = 0; ks < 2; ++ks)
#pragma unroll
    for (int i = 0; i < 4; ++i)
#pragma unroll
      for (int j = 0; j < 4; ++j)
        acc[i][j] = MFMA_BF16(af[ks][i], bf[ks][j], acc[i][j], 0, 0, 0);
}

template<int NSTEP>   // K-tiles of 64 in this wave's range; must be even
__device__ __forceinline__ void gemm_direct(
    const __hip_bfloat16* __restrict__ A,
    const __hip_bfloat16* __restrict__ W,
    int K, int kbeg, long m0, long n0, int lane,
    floatx4 acc[4][4])
{
  const int frow = lane & 15;
  const int fk = lane >> 4;
  const __hip_bfloat16* pa[4];
  const __hip_bfloat16* pw[4];
#pragma unroll
  for (int i = 0; i < 4; ++i) {
    pa[i] = A + (m0 + i * 16 + frow) * (long)K + kbeg + fk * 8;
    pw[i] = W + (n0 + i * 16 + frow) * (long)K + kbeg + fk * 8;
  }
  short8 aA[2][4], bA[2][4], aB[2][4], bB[2][4];
  frag_load(aA, bA, pa, pw, 0);
#pragma unroll 1
  for (int tt = 0; tt < NSTEP / 2; ++tt) {
    frag_load(aB, bB, pa, pw, tt * 128 + 64);
    mfma_step(aA, bA, acc);
    if (tt + 1 < NSTEP / 2) frag_load(aA, bA, pa, pw, tt * 128 + 128);
    mfma_step(aB, bB, acc);
  }
}

// 4-wave K-split reduce: waves 1..3 dump acc (16KB each) into LDS, wave0
// sums. LDS need = 48KB. Returns true for the wave that continues (wave0).
__device__ __forceinline__ bool ks_reduce4(
    floatx4 acc[4][4], float* red, int wid, int lane)
{
  if (wid > 0) {
    float* my = red + (wid - 1) * 4096;
#pragma unroll
    for (int i = 0; i < 4; ++i)
#pragma unroll
      for (int j = 0; j < 4; ++j)
        *(floatx4*)(my + ((i * 4 + j) * 64 + lane) * 4) = acc[i][j];
    WAIT_LGKM0();
  }
  CFENCE(); BARRIER(); CFENCE();
  if (wid > 0) return false;
#pragma unroll
  for (int w = 0; w < 3; ++w)
#pragma unroll
    for (int i = 0; i < 4; ++i)
#pragma unroll
      for (int j = 0; j < 4; ++j)
        acc[i][j] += *(const floatx4*)(red + w * 4096 +
                                       ((i * 4 + j) * 64 + lane) * 4);
  return true;
}

// fp32 store epilogue, N=512. D layout: row=(lane>>4)*4+reg, col=lane&15.
__device__ __forceinline__ void store_f32(
    floatx4 acc[4][4], float* __restrict__ C, const float* __restrict__ bias,
    long m0, long n0, int lane)
{
  const int col_l = lane & 15;
  const int row_l = (lane >> 4) << 2;
#pragma unroll
  for (int j = 0; j < 4; ++j) {
    const long col = n0 + j * 16 + col_l;
    const float bv = bias[col];
#pragma unroll
    for (int i = 0; i < 4; ++i)
#pragma unroll
      for (int r = 0; r < 4; ++r)
        C[(m0 + i * 16 + row_l + r) * 512 + col] = acc[i][j][r] + bv;
  }
}

// bf16 store epilogue (R12: halves intermediate store traffic).
__device__ __forceinline__ void store_bf16(
    floatx4 acc[4][4], __hip_bfloat16* __restrict__ C,
    const float* __restrict__ bias, long m0, long n0, int lane)
{
  const int col_l = lane & 15;
  const int row_l = (lane >> 4) << 2;
#pragma unroll
  for (int j = 0; j < 4; ++j) {
    const long col = n0 + j * 16 + col_l;
    const float bv = bias[col];
#pragma unroll
    for (int i = 0; i < 4; ++i)
#pragma unroll
      for (int r = 0; r < 4; ++r)
        C[(m0 + i * 16 + row_l + r) * 512 + col] =
            __float2bfloat16(acc[i][j][r] + bv);
  }
}

// ---------------------------------------------------------------------------
// QKV launch: grid (64, 8, 3) x 256 threads (4-wave K-split-4, 2 K-tiles
// per wave). z=0: Q = x@Wq^T+bq with fused quantum epilogue -> mix_bf; if
// *gateA != 1 also writes Qb fp32. z=1/2: conditional K/V projections.
// ---------------------------------------------------------------------------
__global__ __launch_bounds__(256, 2) void gemm_qkv(
    const __hip_bfloat16* __restrict__ x_bf,
    const __hip_bfloat16* __restrict__ Wq,
    const __hip_bfloat16* __restrict__ Wk,
    const __hip_bfloat16* __restrict__ Wv,
    const float* __restrict__ bq, const float* __restrict__ bk,
    const float* __restrict__ bvv,
    __hip_bfloat16* __restrict__ mix,
    float* __restrict__ Qb, float* __restrict__ Kb, float* __restrict__ Vb,
    const float* __restrict__ theta, const float* __restrict__ gateA)
{
  const int z = blockIdx.z;
  const float g = *gateA;
  if (z > 0 && g == 1.0f) return;
  const __hip_bfloat16* W = (z == 0) ? Wq : (z == 1) ? Wk : Wv;
  const float* bias = (z == 0) ? bq : (z == 1) ? bk : bvv;
  float* Cf = (z == 0) ? Qb : (z == 1) ? Kb : Vb;

  __shared__ __align__(16) float shred[12288];   // 48 KB: reduce + epilogue
  const int tid = threadIdx.x;
  const int wid = tid >> 6;
  const int lane = tid & 63;
  const long m0 = (long)blockIdx.x * 64;
  const long n0 = (long)blockIdx.y * 64;
  floatx4 acc[4][4];
#pragma unroll
  for (int i = 0; i < 4; ++i)
#pragma unroll
    for (int j = 0; j < 4; ++j) acc[i][j] = (floatx4){0.f, 0.f, 0.f, 0.f};

  gemm_direct<2>(x_bf, W, 512, wid * 128, m0, n0, lane, acc);
  if (!ks_reduce4(acc, shred, wid, lane)) return;   // wave0 continues

  const int col_l = lane & 15;
  const int row_l = (lane >> 4) << 2;

  if (z > 0 || g != 1.0f) store_f32(acc, Cf, bias, m0, n0, lane);
  if (z == 0) {
    // quantum epilogue: LDS-transpose acc(+bias), then per 8-wide head
    // group o[0]=c1..c7, o[j>=1]=c0..cj with c=cos(q+theta). Single wave:
    // DS pipe in-order; data-dep orders red reads before shf overwrite.
    float* shf = shred;   // 64x64 fp32 = 16 KB
    WAIT_LGKM0();
#pragma unroll
    for (int j = 0; j < 4; ++j) {
      const long col = n0 + j * 16 + col_l;
      const float bv = bias[col];
#pragma unroll
      for (int i = 0; i < 4; ++i)
#pragma unroll
        for (int r = 0; r < 4; ++r)
          shf[(i * 16 + row_l + r) * 64 + j * 16 + col_l] = acc[i][j][r] + bv;
    }
    WAIT_LGKM0();
    float th[8];
#pragma unroll
    for (int i = 0; i < 8; ++i) th[i] = theta[i];
#pragma unroll
    for (int t = 0; t < 8; ++t) {
      const int gidx = t * 64 + lane;
      const int row = gidx >> 3;
      const int hh = gidx & 7;
      const float* src = shf + row * 64 + hh * 8;
      float c[8];
#pragma unroll
      for (int i = 0; i < 8; ++i) c[i] = __cosf(src[i] + th[i]);
      float o[8];
      float p = c[1];
#pragma unroll
      for (int i = 2; i < 8; ++i) p *= c[i];
      o[0] = p;
      float cp = c[0];
#pragma unroll
      for (int i = 1; i < 8; ++i) { cp *= c[i]; o[i] = cp; }
      union { unsigned short u16[8]; uint4 v; } pk;
#pragma unroll
      for (int i = 0; i < 8; ++i) pk.u16[i] = f2bf_bits(o[i]);
      *(uint4*)(mix + (m0 + row) * 512 + n0 + hh * 8) = pk.v;
    }
  }
}

// ---------------------------------------------------------------------------
// R13 fused kernel: attn = mix @ Wo^T + bo ; x1 = LN1(x + attn) ;
// qm/xs -> hq (= relu(qm@W1^T+b1)) and cond hc. One block owns 16 rows x
// all 512 cols so the LN row-reduce is block-local.
// grid 256, blockDim 512 (8 waves). Wave w computes cols [64w, 64w+64).
// A-tile (16x64, 2KB) staged by wave0, SHARED by all waves; W-tile 64x64
// private per wave. A ring-3, W ring-2. Counted vmcnt per wave (wave0
// 10/iter = 2 A + 8 W; others 8) + raw s_barrier per K-step — NEVER
// __syncthreads in the loop (drains vmcnt(0), kills the prefetch).
// LDS: A 3x2KB + W 8x2x8KB = 134KB -> 1 block/CU, 8 waves/CU.
// ---------------------------------------------------------------------------
__global__ __launch_bounds__(512) void wo_lnffn(
    const __hip_bfloat16* __restrict__ A,      // mix_bf [4096][512]
    const __hip_bfloat16* __restrict__ W,      // Wo_bf  [512][512]
    const float* __restrict__ bo,
    const float* __restrict__ x,
    const float* __restrict__ lw, const float* __restrict__ lb,
    float* __restrict__ x1, const float* __restrict__ phi,
    const float* __restrict__ W1,              // fp32 [2048][8]
    const float* __restrict__ b1,
    __hip_bfloat16* __restrict__ hq, __hip_bfloat16* __restrict__ hc,
    const float* __restrict__ gateF)
{
  __shared__ __align__(16) __hip_bfloat16 sh[68608];   // 134 KB
  const int tid = threadIdx.x;
  const int wid = tid >> 6;
  const int lane = tid & 63;
  const long m0 = (long)blockIdx.x * 16;
  const long n0w = (long)wid * 64;

  const int srow = lane >> 3;               // 0..7
  const int gchunk = (lane & 7) ^ srow;     // pre-swizzled global source
  const int frow = lane & 15;
  const int fk = lane >> 4;                 // 0..3

  __hip_bfloat16* shA = sh;                       // 3 slots x 1024 bf16
  __hip_bfloat16* shW = sh + 3072 + wid * 8192;   // 2 slots x 4096 bf16

  auto stageA = [&](int kt, int slot) {           // wave 0 only; 2 instrs
    __hip_bfloat16* buf = shA + slot * 1024;
#pragma unroll
    for (int i = 0; i < 2; ++i) {
      const int row = i * 8 + srow;               // 0..15
      GLOBAL_LOAD_LDS16(A + (m0 + row) * 512 + kt + gchunk * 8, buf + i * 512);
    }
  };
  auto stageW = [&](int kt, int slot) {           // 8 instrs
    __hip_bfloat16* buf = shW + slot * 4096;
#pragma unroll
    for (int i = 0; i < 8; ++i) {
      const int row = i * 8 + srow;
      GLOBAL_LOAD_LDS16(W + (n0w + row) * 512 + kt + gchunk * 8, buf + i * 512);
    }
  };

  floatx4 acc[4];
#pragma unroll
  for (int j = 0; j < 4; ++j) acc[j] = (floatx4){0.f, 0.f, 0.f, 0.f};

  // Prologue: wave0 issue order A0,W0,A1,W1 so vmcnt(10) leaves {A1,W1}.
  if (wid == 0) stageA(0, 0);
  stageW(0, 0);
  if (wid == 0) stageA(64, 1);
  stageW(64, 1);

  for (int t = 0; t < 8; ++t) {
    const int wslot = t & 1;
    const int aslot = t % 3;
    if (t < 7) { if (wid == 0) WAIT_VMCNT10(); else WAIT_VMCNT8(); }
    else       { WAIT_VMCNT0(); }
    // wave0 passed its wait => A(t) landed; barrier publishes it to all.
    BARRIER();

    short8 af[2], bf[2][4];
#pragma unroll
    for (int ks = 0; ks < 2; ++ks) {
      af[ks] = *(const short8*)(shA + aslot * 1024 + frow * 64 +
                                (((ks * 4 + fk) ^ (frow & 7)) << 3));
#pragma unroll
      for (int j = 0; j < 4; ++j) {
        const int wr = j * 16 + frow;
        bf[ks][j] = *(const short8*)(shW + wslot * 4096 + wr * 64 +
                                     (((ks * 4 + fk) ^ (wr & 7)) << 3));
      }
    }
    WAIT_LGKM0();                       // frags in VGPR before slot reuse
    if (t < 6) {
      // A(t+2) -> slot (t+2)%3 == (t-1)%3: every wave retired its reads of
      // tile t-1 before reaching this iteration's barrier. W slot private.
      if (wid == 0) stageA((t + 2) << 6, (t + 2) % 3);
      stageW((t + 2) << 6, wslot);
    }
#pragma unroll
    for (int ks = 0; ks < 2; ++ks)
#pragma unroll
      for (int j = 0; j < 4; ++j)
        acc[j] = __builtin_amdgcn_mfma_f32_16x16x32_bf16(
            af[ks], bf[ks][j], acc[j], 0, 0, 0);
  }

  // All waves completed frag reads (own lgkm0 at t=7) before this barrier;
  // attnL (33KB) overlaps shA + shW of waves 0/1 -> barrier REQUIRED.
  BARRIER();

  float* attnL = (float*)sh;            // [16][516] fp32 (pad 516: 2-way max)
  float* qmL = attnL + 16 * 516;        // [16][8]
  float* xsL = qmL + 128;               // [16][8]
  {
    const int col_l = lane & 15;
    const int row_l = (lane >> 4) << 2;
#pragma unroll
    for (int j = 0; j < 4; ++j) {
      const int c = (int)n0w + j * 16 + col_l;
      const float bv = bo[c];
#pragma unroll
      for (int r = 0; r < 4; ++r)
        attnL[(row_l + r) * 516 + c] = acc[j][r] + bv;
    }
  }
  WAIT_LGKM0();
  BARRIER();

  // LN1 over 512 cols: 32 threads per row, shfl-xor reduce within width 32.
  const int rr = tid >> 5;              // 0..15
  const int cl = tid & 31;
  const long rowg = m0 + rr;
  float sv[16];
  float sum = 0.f, ssq = 0.f;
#pragma unroll
  for (int i = 0; i < 16; ++i) {
    const int c = cl + i * 32;
    const float v = x[rowg * 512 + c] + attnL[rr * 516 + c];
    sv[i] = v; sum += v; ssq += v * v;
  }
#pragma unroll
  for (int off = 16; off > 0; off >>= 1) {
    sum += __shfl_xor(sum, off, 32);
    ssq += __shfl_xor(ssq, off, 32);
  }
  const float mean = sum * (1.0f / 512.0f);
  const float var = ssq * (1.0f / 512.0f) - mean * mean;
  const float rstd = rsqrtf(fmaxf(var, 0.0f) + 1e-5f);
#pragma unroll
  for (int i = 0; i < 16; ++i) {
    const int c = cl + i * 32;
    const float o = (sv[i] - mean) * rstd * lw[c] + lb[c];
    x1[rowg * 512 + c] = o;
    if (i == 0 && cl < 8) {
      qmL[rr * 8 + cl] = __cosf(o) * __cosf(phi[cl]);
      xsL[rr * 8 + cl] = o;
    }
  }
  WAIT_LGKM0();
  BARRIER();

  // FFN-h: thread owns outputs n = tid*4 .. tid*4+3 for all 16 rows.
  const int n4 = tid << 2;
  float w1r[4][8];
#pragma unroll
  for (int jr = 0; jr < 4; ++jr) {
    float4 wa = *(const float4*)(W1 + (long)(n4 + jr) * 8);
    float4 wb = *(const float4*)(W1 + (long)(n4 + jr) * 8 + 4);
    w1r[jr][0] = wa.x; w1r[jr][1] = wa.y; w1r[jr][2] = wa.z; w1r[jr][3] = wa.w;
    w1r[jr][4] = wb.x; w1r[jr][5] = wb.y; w1r[jr][6] = wb.z; w1r[jr][7] = wb.w;
  }
  float4 bb = *(const float4*)(b1 + n4);
  const float b1a[4] = {bb.x, bb.y, bb.z, bb.w};
  const float gv = *gateF;
#pragma unroll 2
  for (int r = 0; r < 16; ++r) {
    float qm8[8];
#pragma unroll
    for (int k = 0; k < 8; ++k) qm8[k] = qmL[r * 8 + k];   // LDS broadcast
    union { unsigned short u16[4]; ushort4 v; } pk;
#pragma unroll
    for (int jr = 0; jr < 4; ++jr) {
      float a = b1a[jr];
#pragma unroll
      for (int k = 0; k < 8; ++k) a += qm8[k] * w1r[jr][k];
      pk.u16[jr] = f2bf_bits(fmaxf(a, 0.0f));
    }
    *(ushort4*)(hq + (m0 + r) * 2048 + n4) = pk.v;
    if (gv != 1.0f) {
      float xs8[8];
#pragma unroll
      for (int k = 0; k < 8; ++k) xs8[k] = xsL[r * 8 + k];
#pragma unroll
      for (int jr = 0; jr < 4; ++jr) {
        float a = b1a[jr];
#pragma unroll
        for (int k = 0; k < 8; ++k) a += xs8[k] * w1r[jr][k];
        pk.u16[jr] = f2bf_bits(fmaxf(a, 0.0f));
      }
      *(ushort4*)(hc + (m0 + r) * 2048 + n4) = pk.v;
    }
  }
}

// ---------------------------------------------------------------------------
// FFN-out launch: grid (64, 8, 2) x 256 threads (4-wave K-split-4, 8
// K-tiles per wave). z=0: Fb = hq@W2^T+b2 (bf16). z=1 (cond): Fc.
// ---------------------------------------------------------------------------
__global__ __launch_bounds__(256, 2) void gemm_ffnout(
    const __hip_bfloat16* __restrict__ hq,
    const __hip_bfloat16* __restrict__ hc,
    const __hip_bfloat16* __restrict__ W2, const float* __restrict__ b2,
    __hip_bfloat16* __restrict__ Fb, __hip_bfloat16* __restrict__ Fc,
    const float* __restrict__ gateF)
{
  const int z = blockIdx.z;
  if (z == 1 && *gateF == 1.0f) return;
  const __hip_bfloat16* A = z ? hc : hq;
  __hip_bfloat16* C = z ? Fc : Fb;
  __shared__ __align__(16) float shred[12288];   // 48 KB reduce
  const int tid = threadIdx.x;
  const int wid = tid >> 6;
  const int lane = tid & 63;
  const long m0 = (long)blockIdx.x * 64;
  const long n0 = (long)blockIdx.y * 64;
  floatx4 acc[4][4];
#pragma unroll
  for (int i = 0; i < 4; ++i)
#pragma unroll
    for (int j = 0; j < 4; ++j) acc[i][j] = (floatx4){0.f, 0.f, 0.f, 0.f};
  gemm_direct<8>(A, W2, 2048, wid * 512, m0, n0, lane, acc);
  if (!ks_reduce4(acc, shred, wid, lane)) return;   // wave0 continues
  store_bf16(acc, C, b2, m0, n0, lane);
}

// ---------------------------------------------------------------------------
// input prep: fp32->bf16 for x, Wq, Wo, W2; conditional Wk/Wv.
// (W1 stays fp32 — consumed directly by wo_lnffn.)
// ---------------------------------------------------------------------------
__device__ __forceinline__ void cvt_one(const float* s, __hip_bfloat16* d, int n,
                                        long tid, long stride) {
  const int n4 = n >> 2;
  for (long i = tid; i < n4; i += stride) {
    float4 v = ((const float4*)s)[i];
    ushort4 u;
    u.x = f2bf_bits(v.x); u.y = f2bf_bits(v.y);
    u.z = f2bf_bits(v.z); u.w = f2bf_bits(v.w);
    ((ushort4*)d)[i] = u;
  }
}

__global__ __launch_bounds__(256) void prep_inputs(
    const float* x, __hip_bfloat16* x_bf,
    const float* Wq, __hip_bfloat16* Wq_bf,
    const float* Wo, __hip_bfloat16* Wo_bf,
    const float* W2, __hip_bfloat16* W2_bf,
    const float* Wk, __hip_bfloat16* Wk_bf,
    const float* Wv, __hip_bfloat16* Wv_bf,
    const float* gateA)
{
  const long stride = (long)gridDim.x * blockDim.x;
  const long tid = (long)blockIdx.x * blockDim.x + threadIdx.x;
  cvt_one(x, x_bf, 4096 * 512, tid, stride);
  cvt_one(Wq, Wq_bf, 512 * 512, tid, stride);
  cvt_one(Wo, Wo_bf, 512 * 512, tid, stride);
  cvt_one(W2, W2_bf, 512 * 2048, tid, stride);
  if (*gateA != 1.0f) {
    cvt_one(Wk, Wk_bf, 512 * 512, tid, stride);
    cvt_one(Wv, Wv_bf, 512 * 512, tid, stride);
  }
}

// ---------------------------------------------------------------------------
// [cond gateA!=1] classical softmax attention + blend into mix (bf16).
// ---------------------------------------------------------------------------
__global__ __launch_bounds__(256) void attn_blend(
    const float* __restrict__ Qb, const float* __restrict__ Kb,
    const float* __restrict__ Vb, __hip_bfloat16* __restrict__ mix,
    const float* __restrict__ gateA)
{
  const float g = *gateA;
  if (g == 1.0f) return;
  const int idx = blockIdx.x * blockDim.x + threadIdx.x;
  if (idx >= 4 * 64 * 1024) return;
  const int s = idx & 1023;
  const int h = (idx >> 10) & 63;
  const int b = idx >> 16;
  const long qoff = ((long)(b * 1024 + s)) * 512 + h * 8;
  float q[8];
#pragma unroll
  for (int i = 0; i < 8; ++i) q[i] = Qb[qoff + i] * 0.35355339059327373f;
  float m = -INFINITY, l = 0.0f, acc[8];
#pragma unroll
  for (int i = 0; i < 8; ++i) acc[i] = 0.0f;
  for (int t = 0; t < 1024; ++t) {
    const long koff = ((long)(b * 1024 + t)) * 512 + h * 8;
    const float* kr = Kb + koff;
    const float* vr = Vb + koff;
    float sc = 0.0f;
#pragma unroll
    for (int i = 0; i < 8; ++i) sc += q[i] * kr[i];
    float nm = fmaxf(m, sc);
    float corr = __expf(m - nm);
    float p = __expf(sc - nm);
    l = l * corr + p;
#pragma unroll
    for (int i = 0; i < 8; ++i) acc[i] = acc[i] * corr + p * vr[i];
    m = nm;
  }
  const float inv = 1.0f / l;
  union { unsigned short u16[8]; uint4 v; } pk;
  pk.v = *(const uint4*)(mix + qoff);
#pragma unroll
  for (int i = 0; i < 8; ++i) {
    float quant = bfbits2f(pk.u16[i]);
    pk.u16[i] = f2bf_bits(g * quant + (1.0f - g) * acc[i] * inv);
  }
  *(uint4*)(mix + qoff) = pk.v;
}

// ---------------------------------------------------------------------------
// Final LN: out = LN(x1 + mix(Fb, Fc; gateF)), Fb/Fc bf16 (R12).
// Wave-per-row, 4 rows/block, no barriers. grid 1024.
// ---------------------------------------------------------------------------
__global__ __launch_bounds__(256) void add_ln3(
    const float* __restrict__ x1, const __hip_bfloat16* __restrict__ Fb,
    const __hip_bfloat16* __restrict__ Fc, const float* __restrict__ gateF,
    const float* __restrict__ lw, const float* __restrict__ lb,
    float* __restrict__ out)
{
  const int tid = threadIdx.x;
  const int wv = tid >> 6, lane = tid & 63;
  const int row = blockIdx.x * 4 + wv;
  const long base = (long)row * 512;
  const int c0 = lane * 8;
  float4 a0 = *(const float4*)(x1 + base + c0);
  float4 a1 = *(const float4*)(x1 + base + c0 + 4);
  union { unsigned short u16[8]; uint4 v; } fb;
  fb.v = *(const uint4*)(Fb + base + c0);
  const float xa[8] = {a0.x, a0.y, a0.z, a0.w, a1.x, a1.y, a1.z, a1.w};
  float s[8];
  const float gv = *gateF;
  if (gv != 1.0f) {
    union { unsigned short u16[8]; uint4 v; } fc;
    fc.v = *(const uint4*)(Fc + base + c0);
    const float om = 1.0f - gv;
#pragma unroll
    for (int i = 0; i < 8; ++i)
      s[i] = xa[i] + gv * bfbits2f(fb.u16[i]) + om * bfbits2f(fc.u16[i]);
  } else {
#pragma unroll
    for (int i = 0; i < 8; ++i) s[i] = xa[i] + bfbits2f(fb.u16[i]);
  }
  float sum = 0.f, ssq = 0.f;
#pragma unroll
  for (int i = 0; i < 8; ++i) { sum += s[i]; ssq += s[i] * s[i]; }
#pragma unroll
  for (int off = 32; off > 0; off >>= 1) {
    sum += __shfl_xor(sum, off);
    ssq += __shfl_xor(ssq, off);
  }
  const float mean = sum * (1.0f / 512.0f);
  const float var = ssq * (1.0f / 512.0f) - mean * mean;
  const float rstd = rsqrtf(fmaxf(var, 0.0f) + 1e-5f);
  float4 w0 = *(const float4*)(lw + c0);
  float4 w1 = *(const float4*)(lw + c0 + 4);
  float4 g0 = *(const float4*)(lb + c0);
  float4 g1 = *(const float4*)(lb + c0 + 4);
  const float wf[8] = {w0.x, w0.y, w0.z, w0.w, w1.x, w1.y, w1.z, w1.w};
  const float gf8[8] = {g0.x, g0.y, g0.z, g0.w, g1.x, g1.y, g1.z, g1.w};
  float o[8];
#pragma unroll
  for (int i = 0; i < 8; ++i) o[i] = (s[i] - mean) * rstd * wf[i] + gf8[i];
  *(float4*)(out + base + c0) = (float4){o[0], o[1], o[2], o[3]};
  *(float4*)(out + base + c0 + 4) = (float4){o[4], o[5], o[6], o[7]};
}

// ---------------------------------------------------------------------------
extern "C" void kernel_launch(void* const* d_in, const int* in_sizes, int n_in,
                              void* d_out, int out_size, void* d_ws, size_t ws_size,
                              hipStream_t stream) {
  const float* x     = (const float*)d_in[0];
  const float* Wq    = (const float*)d_in[1];
  const float* bq    = (const float*)d_in[2];
  const float* Wk    = (const float*)d_in[3];
  const float* bk    = (const float*)d_in[4];
  const float* Wv    = (const float*)d_in[5];
  const float* bv    = (const float*)d_in[6];
  const float* theta = (const float*)d_in[7];
  const float* gateA = (const float*)d_in[8];
  const float* Wo    = (const float*)d_in[9];
  const float* bo    = (const float*)d_in[10];
  const float* ln1w  = (const float*)d_in[11];
  const float* ln1b  = (const float*)d_in[12];
  const float* W1    = (const float*)d_in[13];
  const float* b1    = (const float*)d_in[14];
  const float* W2    = (const float*)d_in[15];
  const float* b2    = (const float*)d_in[16];
  const float* phi   = (const float*)d_in[17];
  const float* gateF = (const float*)d_in[18];
  const float* ln2w  = (const float*)d_in[19];
  const float* ln2b  = (const float*)d_in[20];
  float* out = (float*)d_out;

  const size_t MB = 1024 * 1024;
  char* wsb = (char*)d_ws;
  __hip_bfloat16* x_bf    = (__hip_bfloat16*)(wsb + 0 * MB);            // 4 MB
  __hip_bfloat16* Wq_bf   = (__hip_bfloat16*)(wsb + 4 * MB);            // 0.5 MB
  __hip_bfloat16* Wo_bf   = (__hip_bfloat16*)(wsb + 4 * MB + 512 * 1024);
  __hip_bfloat16* W2_bf   = (__hip_bfloat16*)(wsb + 5 * MB);            // 2 MB
  __hip_bfloat16* mix_bf  = (__hip_bfloat16*)(wsb + 8 * MB);            // 4 MB
  float*          x1      = (float*)(wsb + 16 * MB);                    // 8 MB
  __hip_bfloat16* hq_bf   = (__hip_bfloat16*)(wsb + 24 * MB);           // 16 MB
  __hip_bfloat16* Fb_bf   = (__hip_bfloat16*)(wsb + 40 * MB);           // 4 MB
  // conditional (gate != 1) buffers
  float*          Qb      = (float*)(wsb + 52 * MB);                    // 8 MB
  __hip_bfloat16* Wk_bf   = (__hip_bfloat16*)(wsb + 60 * MB);
  __hip_bfloat16* Wv_bf   = (__hip_bfloat16*)(wsb + 60 * MB + 512 * 1024);
  float*          Kb2     = (float*)(wsb + 61 * MB);                    // 8 MB
  float*          Vb2     = (float*)(wsb + 69 * MB);                    // 8 MB
  __hip_bfloat16* hc_bf   = (__hip_bfloat16*)(wsb + 77 * MB);           // 16 MB
  __hip_bfloat16* Fc_bf   = (__hip_bfloat16*)(wsb + 93 * MB);           // 4 MB

  // 1. input prep (all conversions; W1 stays fp32)
  prep_inputs<<<1024, 256, 0, stream>>>(
      x, x_bf, Wq, Wq_bf, Wo, Wo_bf, W2, W2_bf, Wk, Wk_bf, Wv, Wv_bf, gateA);
  // 2. QKV: z=0 Q+quantum -> mix_bf (+Qb cond); z=1/2 K/V (cond)
  gemm_qkv<<<dim3(64, 8, 3), 256, 0, stream>>>(
      x_bf, Wq_bf, Wk_bf, Wv_bf, bq, bk, bv,
      mix_bf, Qb, Kb2, Vb2, theta, gateA);
  // 3. [cond] classical attention + blend into mix_bf
  attn_blend<<<1024, 256, 0, stream>>>(Qb, Kb2, Vb2, mix_bf, gateA);
  // 4. R13 fused: attn = mix@Wo^T+bo ; x1 = LN1(x+attn) ; hq (+hc cond)
  wo_lnffn<<<256, 512, 0, stream>>>(
      mix_bf, Wo_bf, bo, x, ln1w, ln1b, x1, phi, W1, b1, hq_bf, hc_bf, gateF);
  // 5. Fb = hq @ W2^T + b2 (z=0); Fc = hc @ W2^T + b2 (z=1, cond), bf16
  gemm_ffnout<<<dim3(64, 8, 2), 256, 0, stream>>>(
      hq_bf, hc_bf, W2_bf, b2, Fb_bf, Fc_bf, gateF);
  // 6. out = LN(x1 + gF*Fb + (1-gF)*Fc)
  add_ln3<<<1024, 256, 0, stream>>>(x1, Fb_bf, Fc_bf, gateF, ln2w, ln2b, out);
}

// Round 4
// 157.994 us; speedup vs baseline: 1.0628x; 1.0628x over previous
//
#include <hip/hip_runtime.h>
#include <hip/hip_bf16.h>

// Shapes fixed by the problem:
// B=4, S=1024, D=512, H=64, DK=8, FF=2048, NQ=8. Mtok = B*S = 4096.
// R10: multi-dispatch beats persistent mega-kernel.
// R12: bf16 intermediates. R13: wo_lnffn fusion (full-N 16-row blocks).
// R14: K-split-2 LDS-staged qkv/ffnout (-6us). R15: direct-frag GEMM
// REGRESSED +21us (scattered lines, no pipeline depth) -> reverted.
// R16: ffnout re-read analysis: 64x64 tiles re-read hq 8x (128MB) + W2 64x
// (128MB) -> traffic-bound. Rebuilt ffnout on the wo_lnffn skeleton:
// full-N blocks (16 rows x 512 cols, 8 waves, shared A-tile staged by
// wave0, private W ring-2, counted vmcnt + raw s_barrier, 32 K-steps).
// A read ONCE (16MB); W2 L2-resident per XCD. qkv/wo unchanged from R14.

typedef short short8 __attribute__((ext_vector_type(8)));
typedef float floatx4 __attribute__((ext_vector_type(4)));

__device__ __forceinline__ unsigned short f2bf_bits(float f) {
  __hip_bfloat16 h = __float2bfloat16(f);
  return *reinterpret_cast<unsigned short*>(&h);
}
__device__ __forceinline__ float bfbits2f(unsigned short u) {
  union { unsigned int u; float f; } c;
  c.u = (unsigned int)u << 16;
  return c.f;
}

#define GLOBAL_LOAD_LDS16(g, l)                                               \
  __builtin_amdgcn_global_load_lds(                                           \
      (const __attribute__((address_space(1))) void*)(g),                     \
      (__attribute__((address_space(3))) void*)(l), 16, 0, 0)

// Compiler does NOT model global_load_lds's LDS write as aliasing later LDS
// reads (round-3 NaN). Explicit waits, memory clobber pins ordering.
#define WAIT_VMCNT0()   asm volatile("s_waitcnt vmcnt(0)" ::: "memory")
#define WAIT_VMCNT8()   asm volatile("s_waitcnt vmcnt(8)" ::: "memory")
#define WAIT_VMCNT10()  asm volatile("s_waitcnt vmcnt(10)" ::: "memory")
#define WAIT_VMCNT16()  asm volatile("s_waitcnt vmcnt(16)" ::: "memory")
#define WAIT_LGKM0()    asm volatile("s_waitcnt lgkmcnt(0)" ::: "memory")
#define BARRIER()       __builtin_amdgcn_s_barrier()
#define CFENCE()        asm volatile("" ::: "memory")

// ---------------------------------------------------------------------------
// Per-wave GEMM core over a K-range, ring-2 staging (32 KB / wave):
// acc(64x64) += A[:, kr] @ W[:, kr]^T. 4x4 of 16x16x32 MFMA, BK=64.
// XOR chunk swizzle: phys 16B chunk p of row r holds logical chunk
// p ^ (r&7) -> conflict-free ds_read_b128.
// ---------------------------------------------------------------------------
__device__ __forceinline__ void gemm_core_ks(
    const __hip_bfloat16* __restrict__ A,
    const __hip_bfloat16* __restrict__ W,
    int K, int kbeg, int ntiles, long m0, long n0, int lane,
    __hip_bfloat16* sh, floatx4 acc[4][4])
{
  const int srow = lane >> 3;
  const int gchunk = (lane & 7) ^ srow;
  const int frow = lane & 15;
  const int fk = lane >> 4;

  auto stage = [&](int kt, __hip_bfloat16* buf) {
#pragma unroll
    for (int ib = 0; ib < 8; ++ib) {
      const int row = ib * 8 + srow;
      GLOBAL_LOAD_LDS16(A + (m0 + row) * K + kt + gchunk * 8, buf + ib * 512);
      GLOBAL_LOAD_LDS16(W + (n0 + row) * K + kt + gchunk * 8, buf + 4096 + ib * 512);
    }
  };

  WAIT_LGKM0();                         // prior LDS reads retired
  stage(kbeg, sh);
  if (ntiles > 1) stage(kbeg + 64, sh + 8192);

  for (int t = 0; t < ntiles; ++t) {
    __hip_bfloat16* buf = sh + (t & 1) * 8192;
    if (t < ntiles - 1) { WAIT_VMCNT16(); }   // current tile landed
    else               { WAIT_VMCNT0(); }

    short8 af[2][4], bf[2][4];
#pragma unroll
    for (int ks = 0; ks < 2; ++ks)
#pragma unroll
      for (int i = 0; i < 4; ++i) {
        const int ar = i * 16 + frow;
        af[ks][i] = *(const short8*)(buf + ar * 64 + (((ks * 4 + fk) ^ (ar & 7)) << 3));
        bf[ks][i] = *(const short8*)(buf + 4096 + ar * 64 + (((ks * 4 + fk) ^ (ar & 7)) << 3));
      }
    WAIT_LGKM0();                       // frags in VGPR before buf reuse
    if (t + 2 < ntiles) stage(kbeg + ((t + 2) << 6), buf);
#pragma unroll
    for (int ks = 0; ks < 2; ++ks)
#pragma unroll
      for (int i = 0; i < 4; ++i)
#pragma unroll
        for (int j = 0; j < 4; ++j)
          acc[i][j] = __builtin_amdgcn_mfma_f32_16x16x32_bf16(
              af[ks][i], bf[ks][j], acc[i][j], 0, 0, 0);
  }
}

// K-split reduce: wave1 dumps acc into its own ring slot 0 (16 KB fp32),
// wave0 adds. Returns true for the wave that continues (wave0).
__device__ __forceinline__ bool ks_reduce(
    floatx4 acc[4][4], __hip_bfloat16* sh, int wid, int lane)
{
  float* red = (float*)(sh + 16384);    // wave1 ring, slot 0
  if (wid == 1) {
#pragma unroll
    for (int i = 0; i < 4; ++i)
#pragma unroll
      for (int j = 0; j < 4; ++j)
        *(floatx4*)(red + ((i * 4 + j) * 64 + lane) * 4) = acc[i][j];
    WAIT_LGKM0();
  }
  CFENCE(); BARRIER(); CFENCE();
  if (wid == 1) return false;
#pragma unroll
  for (int i = 0; i < 4; ++i)
#pragma unroll
    for (int j = 0; j < 4; ++j)
      acc[i][j] += *(const floatx4*)(red + ((i * 4 + j) * 64 + lane) * 4);
  return true;
}

// fp32 store epilogue, N=512. D layout: row=(lane>>4)*4+reg, col=lane&15.
__device__ __forceinline__ void store_f32(
    floatx4 acc[4][4], float* __restrict__ C, const float* __restrict__ bias,
    long m0, long n0, int lane)
{
  const int col_l = lane & 15;
  const int row_l = (lane >> 4) << 2;
#pragma unroll
  for (int j = 0; j < 4; ++j) {
    const long col = n0 + j * 16 + col_l;
    const float bv = bias[col];
#pragma unroll
    for (int i = 0; i < 4; ++i)
#pragma unroll
      for (int r = 0; r < 4; ++r)
        C[(m0 + i * 16 + row_l + r) * 512 + col] = acc[i][j][r] + bv;
  }
}

// ---------------------------------------------------------------------------
// QKV launch: grid (64, 8, 3) x 128 threads (2-wave K-split). z=0:
// Q = x@Wq^T+bq with fused quantum epilogue -> mix_bf (bf16); if *gateA != 1
// also writes Qb fp32. z=1/2: conditional K/V projections.
// ---------------------------------------------------------------------------
__global__ __launch_bounds__(128) void gemm_qkv(
    const __hip_bfloat16* __restrict__ x_bf,
    const __hip_bfloat16* __restrict__ Wq,
    const __hip_bfloat16* __restrict__ Wk,
    const __hip_bfloat16* __restrict__ Wv,
    const float* __restrict__ bq, const float* __restrict__ bk,
    const float* __restrict__ bvv,
    __hip_bfloat16* __restrict__ mix,
    float* __restrict__ Qb, float* __restrict__ Kb, float* __restrict__ Vb,
    const float* __restrict__ theta, const float* __restrict__ gateA)
{
  const int z = blockIdx.z;
  const float g = *gateA;
  if (z > 0 && g == 1.0f) return;
  const __hip_bfloat16* W = (z == 0) ? Wq : (z == 1) ? Wk : Wv;
  const float* bias = (z == 0) ? bq : (z == 1) ? bk : bvv;
  float* Cf = (z == 0) ? Qb : (z == 1) ? Kb : Vb;

  __shared__ __align__(16) __hip_bfloat16 sh[32768];   // 64 KB: 2 x ring-2
  const int tid = threadIdx.x;
  const int wid = tid >> 6;
  const int lane = tid & 63;
  const long m0 = (long)blockIdx.x * 64;
  const long n0 = (long)blockIdx.y * 64;
  floatx4 acc[4][4];
#pragma unroll
  for (int i = 0; i < 4; ++i)
#pragma unroll
    for (int j = 0; j < 4; ++j) acc[i][j] = (floatx4){0.f, 0.f, 0.f, 0.f};

  gemm_core_ks(x_bf, W, 512, wid * 256, 4, m0, n0, lane, sh + wid * 16384, acc);
  if (!ks_reduce(acc, sh, wid, lane)) return;   // wave0 continues

  const int col_l = lane & 15;
  const int row_l = (lane >> 4) << 2;

  if (z > 0 || g != 1.0f) store_f32(acc, Cf, bias, m0, n0, lane);
  if (z == 0) {
    // quantum epilogue: LDS-transpose acc(+bias), then per 8-wide head
    // group o[0]=c1..c7, o[j>=1]=c0..cj with c=cos(q+theta). Single wave:
    // DS pipe in-order; lgkm fences pin ordering/completion. shf uses
    // wave0's ring [0,16KB) — no overlap with red buffer at [32KB,48KB).
    float* shf = (float*)sh;   // 64x64 fp32 = 16 KB
    WAIT_LGKM0();
#pragma unroll
    for (int j = 0; j < 4; ++j) {
      const long col = n0 + j * 16 + col_l;
      const float bv = bias[col];
#pragma unroll
      for (int i = 0; i < 4; ++i)
#pragma unroll
        for (int r = 0; r < 4; ++r)
          shf[(i * 16 + row_l + r) * 64 + j * 16 + col_l] = acc[i][j][r] + bv;
    }
    WAIT_LGKM0();
    float th[8];
#pragma unroll
    for (int i = 0; i < 8; ++i) th[i] = theta[i];
#pragma unroll
    for (int t = 0; t < 8; ++t) {
      const int gidx = t * 64 + lane;
      const int row = gidx >> 3;
      const int hh = gidx & 7;
      const float* src = shf + row * 64 + hh * 8;
      float c[8];
#pragma unroll
      for (int i = 0; i < 8; ++i) c[i] = __cosf(src[i] + th[i]);
      float o[8];
      float p = c[1];
#pragma unroll
      for (int i = 2; i < 8; ++i) p *= c[i];
      o[0] = p;
      float cp = c[0];
#pragma unroll
      for (int i = 1; i < 8; ++i) { cp *= c[i]; o[i] = cp; }
      union { unsigned short u16[8]; uint4 v; } pk;
#pragma unroll
      for (int i = 0; i < 8; ++i) pk.u16[i] = f2bf_bits(o[i]);
      *(uint4*)(mix + (m0 + row) * 512 + n0 + hh * 8) = pk.v;
    }
  }
}

// ---------------------------------------------------------------------------
// R13 fused kernel: attn = mix @ Wo^T + bo ; x1 = LN1(x + attn) ;
// qm/xs -> hq (= relu(qm@W1^T+b1)) and cond hc. One block owns 16 rows x
// all 512 cols so the LN row-reduce is block-local.
// grid 256, blockDim 512 (8 waves). Wave w computes cols [64w, 64w+64).
// A-tile (16x64, 2KB) staged by wave0, SHARED by all waves; W-tile 64x64
// private per wave. A ring-3, W ring-2. Counted vmcnt per wave (wave0
// 10/iter = 2 A + 8 W; others 8) + raw s_barrier per K-step — NEVER
// __syncthreads in the loop (drains vmcnt(0), kills the prefetch).
// LDS: A 3x2KB + W 8x2x8KB = 134KB -> 1 block/CU, 8 waves/CU.
// ---------------------------------------------------------------------------
__global__ __launch_bounds__(512) void wo_lnffn(
    const __hip_bfloat16* __restrict__ A,      // mix_bf [4096][512]
    const __hip_bfloat16* __restrict__ W,      // Wo_bf  [512][512]
    const float* __restrict__ bo,
    const float* __restrict__ x,
    const float* __restrict__ lw, const float* __restrict__ lb,
    float* __restrict__ x1, const float* __restrict__ phi,
    const float* __restrict__ W1,              // fp32 [2048][8]
    const float* __restrict__ b1,
    __hip_bfloat16* __restrict__ hq, __hip_bfloat16* __restrict__ hc,
    const float* __restrict__ gateF)
{
  __shared__ __align__(16) __hip_bfloat16 sh[68608];   // 134 KB
  const int tid = threadIdx.x;
  const int wid = tid >> 6;
  const int lane = tid & 63;
  const long m0 = (long)blockIdx.x * 16;
  const long n0w = (long)wid * 64;

  const int srow = lane >> 3;               // 0..7
  const int gchunk = (lane & 7) ^ srow;     // pre-swizzled global source
  const int frow = lane & 15;
  const int fk = lane >> 4;                 // 0..3

  __hip_bfloat16* shA = sh;                       // 3 slots x 1024 bf16
  __hip_bfloat16* shW = sh + 3072 + wid * 8192;   // 2 slots x 4096 bf16

  auto stageA = [&](int kt, int slot) {           // wave 0 only; 2 instrs
    __hip_bfloat16* buf = shA + slot * 1024;
#pragma unroll
    for (int i = 0; i < 2; ++i) {
      const int row = i * 8 + srow;               // 0..15
      GLOBAL_LOAD_LDS16(A + (m0 + row) * 512 + kt + gchunk * 8, buf + i * 512);
    }
  };
  auto stageW = [&](int kt, int slot) {           // 8 instrs
    __hip_bfloat16* buf = shW + slot * 4096;
#pragma unroll
    for (int i = 0; i < 8; ++i) {
      const int row = i * 8 + srow;
      GLOBAL_LOAD_LDS16(W + (n0w + row) * 512 + kt + gchunk * 8, buf + i * 512);
    }
  };

  floatx4 acc[4];
#pragma unroll
  for (int j = 0; j < 4; ++j) acc[j] = (floatx4){0.f, 0.f, 0.f, 0.f};

  // Prologue: wave0 issue order A0,W0,A1,W1 so vmcnt(10) leaves {A1,W1}.
  if (wid == 0) stageA(0, 0);
  stageW(0, 0);
  if (wid == 0) stageA(64, 1);
  stageW(64, 1);

  for (int t = 0; t < 8; ++t) {
    const int wslot = t & 1;
    const int aslot = t % 3;
    if (t < 7) { if (wid == 0) WAIT_VMCNT10(); else WAIT_VMCNT8(); }
    else       { WAIT_VMCNT0(); }
    // wave0 passed its wait => A(t) landed; barrier publishes it to all.
    BARRIER();

    short8 af[2], bf[2][4];
#pragma unroll
    for (int ks = 0; ks < 2; ++ks) {
      af[ks] = *(const short8*)(shA + aslot * 1024 + frow * 64 +
                                (((ks * 4 + fk) ^ (frow & 7)) << 3));
#pragma unroll
      for (int j = 0; j < 4; ++j) {
        const int wr = j * 16 + frow;
        bf[ks][j] = *(const short8*)(shW + wslot * 4096 + wr * 64 +
                                     (((ks * 4 + fk) ^ (wr & 7)) << 3));
      }
    }
    WAIT_LGKM0();                       // frags in VGPR before slot reuse
    if (t < 6) {
      // A(t+2) -> slot (t+2)%3 == (t-1)%3: every wave retired its reads of
      // tile t-1 before reaching this iteration's barrier. W slot private.
      if (wid == 0) stageA((t + 2) << 6, (t + 2) % 3);
      stageW((t + 2) << 6, wslot);
    }
#pragma unroll
    for (int ks = 0; ks < 2; ++ks)
#pragma unroll
      for (int j = 0; j < 4; ++j)
        acc[j] = __builtin_amdgcn_mfma_f32_16x16x32_bf16(
            af[ks], bf[ks][j], acc[j], 0, 0, 0);
  }

  // All waves completed frag reads (own lgkm0 at t=7) before this barrier;
  // attnL (33KB) overlaps shA + shW of waves 0/1 -> barrier REQUIRED.
  BARRIER();

  float* attnL = (float*)sh;            // [16][516] fp32 (pad 516: 2-way max)
  float* qmL = attnL + 16 * 516;        // [16][8]
  float* xsL = qmL + 128;               // [16][8]
  {
    const int col_l = lane & 15;
    const int row_l = (lane >> 4) << 2;
#pragma unroll
    for (int j = 0; j < 4; ++j) {
      const int c = (int)n0w + j * 16 + col_l;
      const float bv = bo[c];
#pragma unroll
      for (int r = 0; r < 4; ++r)
        attnL[(row_l + r) * 516 + c] = acc[j][r] + bv;
    }
  }
  WAIT_LGKM0();
  BARRIER();

  // LN1 over 512 cols: 32 threads per row, shfl-xor reduce within width 32.
  const int rr = tid >> 5;              // 0..15
  const int cl = tid & 31;
  const long rowg = m0 + rr;
  float sv[16];
  float sum = 0.f, ssq = 0.f;
#pragma unroll
  for (int i = 0; i < 16; ++i) {
    const int c = cl + i * 32;
    const float v = x[rowg * 512 + c] + attnL[rr * 516 + c];
    sv[i] = v; sum += v; ssq += v * v;
  }
#pragma unroll
  for (int off = 16; off > 0; off >>= 1) {
    sum += __shfl_xor(sum, off, 32);
    ssq += __shfl_xor(ssq, off, 32);
  }
  const float mean = sum * (1.0f / 512.0f);
  const float var = ssq * (1.0f / 512.0f) - mean * mean;
  const float rstd = rsqrtf(fmaxf(var, 0.0f) + 1e-5f);
#pragma unroll
  for (int i = 0; i < 16; ++i) {
    const int c = cl + i * 32;
    const float o = (sv[i] - mean) * rstd * lw[c] + lb[c];
    x1[rowg * 512 + c] = o;
    if (i == 0 && cl < 8) {
      qmL[rr * 8 + cl] = __cosf(o) * __cosf(phi[cl]);
      xsL[rr * 8 + cl] = o;
    }
  }
  WAIT_LGKM0();
  BARRIER();

  // FFN-h: thread owns outputs n = tid*4 .. tid*4+3 for all 16 rows.
  const int n4 = tid << 2;
  float w1r[4][8];
#pragma unroll
  for (int jr = 0; jr < 4; ++jr) {
    float4 wa = *(const float4*)(W1 + (long)(n4 + jr) * 8);
    float4 wb = *(const float4*)(W1 + (long)(n4 + jr) * 8 + 4);
    w1r[jr][0] = wa.x; w1r[jr][1] = wa.y; w1r[jr][2] = wa.z; w1r[jr][3] = wa.w;
    w1r[jr][4] = wb.x; w1r[jr][5] = wb.y; w1r[jr][6] = wb.z; w1r[jr][7] = wb.w;
  }
  float4 bb = *(const float4*)(b1 + n4);
  const float b1a[4] = {bb.x, bb.y, bb.z, bb.w};
  const float gv = *gateF;
#pragma unroll 2
  for (int r = 0; r < 16; ++r) {
    float qm8[8];
#pragma unroll
    for (int k = 0; k < 8; ++k) qm8[k] = qmL[r * 8 + k];   // LDS broadcast
    union { unsigned short u16[4]; ushort4 v; } pk;
#pragma unroll
    for (int jr = 0; jr < 4; ++jr) {
      float a = b1a[jr];
#pragma unroll
      for (int k = 0; k < 8; ++k) a += qm8[k] * w1r[jr][k];
      pk.u16[jr] = f2bf_bits(fmaxf(a, 0.0f));
    }
    *(ushort4*)(hq + (m0 + r) * 2048 + n4) = pk.v;
    if (gv != 1.0f) {
      float xs8[8];
#pragma unroll
      for (int k = 0; k < 8; ++k) xs8[k] = xsL[r * 8 + k];
#pragma unroll
      for (int jr = 0; jr < 4; ++jr) {
        float a = b1a[jr];
#pragma unroll
        for (int k = 0; k < 8; ++k) a += xs8[k] * w1r[jr][k];
        pk.u16[jr] = f2bf_bits(fmaxf(a, 0.0f));
      }
      *(ushort4*)(hc + (m0 + r) * 2048 + n4) = pk.v;
    }
  }
}

// ---------------------------------------------------------------------------
// R16 FFN-out: full-N blocks on the wo_lnffn skeleton. grid (256, 2) x 512
// threads. Block = 16 rows x 512 cols; wave w owns cols [64w, 64w+64);
// K=2048 in 32 steps. Wave0 stages the SHARED 16x64 A-tile (ring-3, hq rows
// read ONCE total); each wave stages its private 64x64 W2-tile (ring-2,
// L2-resident). Counted vmcnt (wave0 10 = 2A+8W, others 8) + raw s_barrier
// per step. z=1 (cond gateF!=1): hc -> Fc. LDS 134KB -> 1 block/CU, 8 waves.
// ---------------------------------------------------------------------------
__global__ __launch_bounds__(512) void gemm_ffnout(
    const __hip_bfloat16* __restrict__ hq,
    const __hip_bfloat16* __restrict__ hc,
    const __hip_bfloat16* __restrict__ W2, const float* __restrict__ b2,
    __hip_bfloat16* __restrict__ Fb, __hip_bfloat16* __restrict__ Fc,
    const float* __restrict__ gateF)
{
  const int z = blockIdx.y;
  if (z == 1 && *gateF == 1.0f) return;
  const __hip_bfloat16* A = z ? hc : hq;
  __hip_bfloat16* C = z ? Fc : Fb;

  __shared__ __align__(16) __hip_bfloat16 sh[68608];   // 134 KB
  const int tid = threadIdx.x;
  const int wid = tid >> 6;
  const int lane = tid & 63;
  const long m0 = (long)blockIdx.x * 16;
  const long n0w = (long)wid * 64;

  const int srow = lane >> 3;
  const int gchunk = (lane & 7) ^ srow;
  const int frow = lane & 15;
  const int fk = lane >> 4;

  __hip_bfloat16* shA = sh;                       // 3 slots x 1024 bf16
  __hip_bfloat16* shW = sh + 3072 + wid * 8192;   // 2 slots x 4096 bf16

  auto stageA = [&](int kt, int slot) {           // wave 0 only; 2 instrs
    __hip_bfloat16* buf = shA + slot * 1024;
#pragma unroll
    for (int i = 0; i < 2; ++i) {
      const int row = i * 8 + srow;               // 0..15
      GLOBAL_LOAD_LDS16(A + (m0 + row) * 2048 + kt + gchunk * 8, buf + i * 512);
    }
  };
  auto stageW = [&](int kt, int slot) {           // 8 instrs
    __hip_bfloat16* buf = shW + slot * 4096;
#pragma unroll
    for (int i = 0; i < 8; ++i) {
      const int row = i * 8 + srow;
      GLOBAL_LOAD_LDS16(W2 + (n0w + row) * 2048 + kt + gchunk * 8, buf + i * 512);
    }
  };

  floatx4 acc[4];
#pragma unroll
  for (int j = 0; j < 4; ++j) acc[j] = (floatx4){0.f, 0.f, 0.f, 0.f};

  // Prologue: wave0 issue order A0,W0,A1,W1 so vmcnt(10) leaves {A1,W1}.
  if (wid == 0) stageA(0, 0);
  stageW(0, 0);
  if (wid == 0) stageA(64, 1);
  stageW(64, 1);

  for (int t = 0; t < 32; ++t) {
    const int wslot = t & 1;
    const int aslot = t % 3;
    if (t < 31) { if (wid == 0) WAIT_VMCNT10(); else WAIT_VMCNT8(); }
    else        { WAIT_VMCNT0(); }
    // wave0 passed its wait => A(t) landed; barrier publishes it to all.
    BARRIER();

    short8 af[2], bf[2][4];
#pragma unroll
    for (int ks = 0; ks < 2; ++ks) {
      af[ks] = *(const short8*)(shA + aslot * 1024 + frow * 64 +
                                (((ks * 4 + fk) ^ (frow & 7)) << 3));
#pragma unroll
      for (int j = 0; j < 4; ++j) {
        const int wr = j * 16 + frow;
        bf[ks][j] = *(const short8*)(shW + wslot * 4096 + wr * 64 +
                                     (((ks * 4 + fk) ^ (wr & 7)) << 3));
      }
    }
    WAIT_LGKM0();                       // frags in VGPR before slot reuse
    if (t < 30) {
      // A(t+2) -> slot (t+2)%3 == (t-1)%3: all waves retired tile t-1 reads
      // before this iteration's barrier. W slot private.
      if (wid == 0) stageA((t + 2) << 6, (t + 2) % 3);
      stageW((t + 2) << 6, wslot);
    }
#pragma unroll
    for (int ks = 0; ks < 2; ++ks)
#pragma unroll
      for (int j = 0; j < 4; ++j)
        acc[j] = __builtin_amdgcn_mfma_f32_16x16x32_bf16(
            af[ks], bf[ks][j], acc[j], 0, 0, 0);
  }

  // bf16 + bias store: 16 rows x 64 cols per wave.
  const int col_l = lane & 15;
  const int row_l = (lane >> 4) << 2;
#pragma unroll
  for (int j = 0; j < 4; ++j) {
    const long col = n0w + j * 16 + col_l;
    const float bv = b2[col];
#pragma unroll
    for (int r = 0; r < 4; ++r)
      C[(m0 + row_l + r) * 512 + col] = __float2bfloat16(acc[j][r] + bv);
  }
}

// ---------------------------------------------------------------------------
// input prep: fp32->bf16 for x, Wq, Wo, W2; conditional Wk/Wv.
// (W1 stays fp32 — consumed directly by wo_lnffn.)
// ---------------------------------------------------------------------------
__device__ __forceinline__ void cvt_one(const float* s, __hip_bfloat16* d, int n,
                                        long tid, long stride) {
  const int n4 = n >> 2;
  for (long i = tid; i < n4; i += stride) {
    float4 v = ((const float4*)s)[i];
    ushort4 u;
    u.x = f2bf_bits(v.x); u.y = f2bf_bits(v.y);
    u.z = f2bf_bits(v.z); u.w = f2bf_bits(v.w);
    ((ushort4*)d)[i] = u;
  }
}

__global__ __launch_bounds__(256) void prep_inputs(
    const float* x, __hip_bfloat16* x_bf,
    const float* Wq, __hip_bfloat16* Wq_bf,
    const float* Wo, __hip_bfloat16* Wo_bf,
    const float* W2, __hip_bfloat16* W2_bf,
    const float* Wk, __hip_bfloat16* Wk_bf,
    const float* Wv, __hip_bfloat16* Wv_bf,
    const float* gateA)
{
  const long stride = (long)gridDim.x * blockDim.x;
  const long tid = (long)blockIdx.x * blockDim.x + threadIdx.x;
  cvt_one(x, x_bf, 4096 * 512, tid, stride);
  cvt_one(Wq, Wq_bf, 512 * 512, tid, stride);
  cvt_one(Wo, Wo_bf, 512 * 512, tid, stride);
  cvt_one(W2, W2_bf, 512 * 2048, tid, stride);
  if (*gateA != 1.0f) {
    cvt_one(Wk, Wk_bf, 512 * 512, tid, stride);
    cvt_one(Wv, Wv_bf, 512 * 512, tid, stride);
  }
}

// ---------------------------------------------------------------------------
// [cond gateA!=1] classical softmax attention + blend into mix (bf16).
// ---------------------------------------------------------------------------
__global__ __launch_bounds__(256) void attn_blend(
    const float* __restrict__ Qb, const float* __restrict__ Kb,
    const float* __restrict__ Vb, __hip_bfloat16* __restrict__ mix,
    const float* __restrict__ gateA)
{
  const float g = *gateA;
  if (g == 1.0f) return;
  const int idx = blockIdx.x * blockDim.x + threadIdx.x;
  if (idx >= 4 * 64 * 1024) return;
  const int s = idx & 1023;
  const int h = (idx >> 10) & 63;
  const int b = idx >> 16;
  const long qoff = ((long)(b * 1024 + s)) * 512 + h * 8;
  float q[8];
#pragma unroll
  for (int i = 0; i < 8; ++i) q[i] = Qb[qoff + i] * 0.35355339059327373f;
  float m = -INFINITY, l = 0.0f, acc[8];
#pragma unroll
  for (int i = 0; i < 8; ++i) acc[i] = 0.0f;
  for (int t = 0; t < 1024; ++t) {
    const long koff = ((long)(b * 1024 + t)) * 512 + h * 8;
    const float* kr = Kb + koff;
    const float* vr = Vb + koff;
    float sc = 0.0f;
#pragma unroll
    for (int i = 0; i < 8; ++i) sc += q[i] * kr[i];
    float nm = fmaxf(m, sc);
    float corr = __expf(m - nm);
    float p = __expf(sc - nm);
    l = l * corr + p;
#pragma unroll
    for (int i = 0; i < 8; ++i) acc[i] = acc[i] * corr + p * vr[i];
    m = nm;
  }
  const float inv = 1.0f / l;
  union { unsigned short u16[8]; uint4 v; } pk;
  pk.v = *(const uint4*)(mix + qoff);
#pragma unroll
  for (int i = 0; i < 8; ++i) {
    float quant = bfbits2f(pk.u16[i]);
    pk.u16[i] = f2bf_bits(g * quant + (1.0f - g) * acc[i] * inv);
  }
  *(uint4*)(mix + qoff) = pk.v;
}

// ---------------------------------------------------------------------------
// Final LN: out = LN(x1 + mix(Fb, Fc; gateF)), Fb/Fc bf16 (R12).
// Wave-per-row, 4 rows/block, no barriers. grid 1024.
// ---------------------------------------------------------------------------
__global__ __launch_bounds__(256) void add_ln3(
    const float* __restrict__ x1, const __hip_bfloat16* __restrict__ Fb,
    const __hip_bfloat16* __restrict__ Fc, const float* __restrict__ gateF,
    const float* __restrict__ lw, const float* __restrict__ lb,
    float* __restrict__ out)
{
  const int tid = threadIdx.x;
  const int wv = tid >> 6, lane = tid & 63;
  const int row = blockIdx.x * 4 + wv;
  const long base = (long)row * 512;
  const int c0 = lane * 8;
  float4 a0 = *(const float4*)(x1 + base + c0);
  float4 a1 = *(const float4*)(x1 + base + c0 + 4);
  union { unsigned short u16[8]; uint4 v; } fb;
  fb.v = *(const uint4*)(Fb + base + c0);
  const float xa[8] = {a0.x, a0.y, a0.z, a0.w, a1.x, a1.y, a1.z, a1.w};
  float s[8];
  const float gv = *gateF;
  if (gv != 1.0f) {
    union { unsigned short u16[8]; uint4 v; } fc;
    fc.v = *(const uint4*)(Fc + base + c0);
    const float om = 1.0f - gv;
#pragma unroll
    for (int i = 0; i < 8; ++i)
      s[i] = xa[i] + gv * bfbits2f(fb.u16[i]) + om * bfbits2f(fc.u16[i]);
  } else {
#pragma unroll
    for (int i = 0; i < 8; ++i) s[i] = xa[i] + bfbits2f(fb.u16[i]);
  }
  float sum = 0.f, ssq = 0.f;
#pragma unroll
  for (int i = 0; i < 8; ++i) { sum += s[i]; ssq += s[i] * s[i]; }
#pragma unroll
  for (int off = 32; off > 0; off >>= 1) {
    sum += __shfl_xor(sum, off);
    ssq += __shfl_xor(ssq, off);
  }
  const float mean = sum * (1.0f / 512.0f);
  const float var = ssq * (1.0f / 512.0f) - mean * mean;
  const float rstd = rsqrtf(fmaxf(var, 0.0f) + 1e-5f);
  float4 w0 = *(const float4*)(lw + c0);
  float4 w1 = *(const float4*)(lw + c0 + 4);
  float4 g0 = *(const float4*)(lb + c0);
  float4 g1 = *(const float4*)(lb + c0 + 4);
  const float wf[8] = {w0.x, w0.y, w0.z, w0.w, w1.x, w1.y, w1.z, w1.w};
  const float gf8[8] = {g0.x, g0.y, g0.z, g0.w, g1.x, g1.y, g1.z, g1.w};
  float o[8];
#pragma unroll
  for (int i = 0; i < 8; ++i) o[i] = (s[i] - mean) * rstd * wf[i] + gf8[i];
  *(float4*)(out + base + c0) = (float4){o[0], o[1], o[2], o[3]};
  *(float4*)(out + base + c0 + 4) = (float4){o[4], o[5], o[6], o[7]};
}

// ---------------------------------------------------------------------------
extern "C" void kernel_launch(void* const* d_in, const int* in_sizes, int n_in,
                              void* d_out, int out_size, void* d_ws, size_t ws_size,
                              hipStream_t stream) {
  const float* x     = (const float*)d_in[0];
  const float* Wq    = (const float*)d_in[1];
  const float* bq    = (const float*)d_in[2];
  const float* Wk    = (const float*)d_in[3];
  const float* bk    = (const float*)d_in[4];
  const float* Wv    = (const float*)d_in[5];
  const float* bv    = (const float*)d_in[6];
  const float* theta = (const float*)d_in[7];
  const float* gateA = (const float*)d_in[8];
  const float* Wo    = (const float*)d_in[9];
  const float* bo    = (const float*)d_in[10];
  const float* ln1w  = (const float*)d_in[11];
  const float* ln1b  = (const float*)d_in[12];
  const float* W1    = (const float*)d_in[13];
  const float* b1    = (const float*)d_in[14];
  const float* W2    = (const float*)d_in[15];
  const float* b2    = (const float*)d_in[16];
  const float* phi   = (const float*)d_in[17];
  const float* gateF = (const float*)d_in[18];
  const float* ln2w  = (const float*)d_in[19];
  const float* ln2b  = (const float*)d_in[20];
  float* out = (float*)d_out;

  const size_t MB = 1024 * 1024;
  char* wsb = (char*)d_ws;
  __hip_bfloat16* x_bf    = (__hip_bfloat16*)(wsb + 0 * MB);            // 4 MB
  __hip_bfloat16* Wq_bf   = (__hip_bfloat16*)(wsb + 4 * MB);            // 0.5 MB
  __hip_bfloat16* Wo_bf   = (__hip_bfloat16*)(wsb + 4 * MB + 512 * 1024);
  __hip_bfloat16* W2_bf   = (__hip_bfloat16*)(wsb + 5 * MB);            // 2 MB
  __hip_bfloat16* mix_bf  = (__hip_bfloat16*)(wsb + 8 * MB);            // 4 MB
  float*          x1      = (float*)(wsb + 16 * MB);                    // 8 MB
  __hip_bfloat16* hq_bf   = (__hip_bfloat16*)(wsb + 24 * MB);           // 16 MB
  __hip_bfloat16* Fb_bf   = (__hip_bfloat16*)(wsb + 40 * MB);           // 4 MB
  // conditional (gate != 1) buffers
  float*          Qb      = (float*)(wsb + 52 * MB);                    // 8 MB
  __hip_bfloat16* Wk_bf   = (__hip_bfloat16*)(wsb + 60 * MB);
  __hip_bfloat16* Wv_bf   = (__hip_bfloat16*)(wsb + 60 * MB + 512 * 1024);
  float*          Kb2     = (float*)(wsb + 61 * MB);                    // 8 MB
  float*          Vb2     = (float*)(wsb + 69 * MB);                    // 8 MB
  __hip_bfloat16* hc_bf   = (__hip_bfloat16*)(wsb + 77 * MB);           // 16 MB
  __hip_bfloat16* Fc_bf   = (__hip_bfloat16*)(wsb + 93 * MB);           // 4 MB

  // 1. input prep (all conversions; W1 stays fp32)
  prep_inputs<<<1024, 256, 0, stream>>>(
      x, x_bf, Wq, Wq_bf, Wo, Wo_bf, W2, W2_bf, Wk, Wk_bf, Wv, Wv_bf, gateA);
  // 2. QKV: z=0 Q+quantum -> mix_bf (+Qb cond); z=1/2 K/V (cond)
  gemm_qkv<<<dim3(64, 8, 3), 128, 0, stream>>>(
      x_bf, Wq_bf, Wk_bf, Wv_bf, bq, bk, bv,
      mix_bf, Qb, Kb2, Vb2, theta, gateA);
  // 3. [cond] classical attention + blend into mix_bf
  attn_blend<<<1024, 256, 0, stream>>>(Qb, Kb2, Vb2, mix_bf, gateA);
  // 4. R13 fused: attn = mix@Wo^T+bo ; x1 = LN1(x+attn) ; hq (+hc cond)
  wo_lnffn<<<256, 512, 0, stream>>>(
      mix_bf, Wo_bf, bo, x, ln1w, ln1b, x1, phi, W1, b1, hq_bf, hc_bf, gateF);
  // 5. R16 full-N: Fb = hq@W2^T+b2 (y=0); Fc = hc@W2^T+b2 (y=1, cond)
  gemm_ffnout<<<dim3(256, 2), 512, 0, stream>>>(
      hq_bf, hc_bf, W2_bf, b2, Fb_bf, Fc_bf, gateF);
  // 6. out = LN(x1 + gF*Fb + (1-gF)*Fc)
  add_ln3<<<1024, 256, 0, stream>>>(x1, Fb_bf, Fc_bf, gateF, ln2w, ln2b, out);
}

// Round 5
// 149.510 us; speedup vs baseline: 1.1231x; 1.0567x over previous
//
#include <hip/hip_runtime.h>
#include <hip/hip_bf16.h>

// Shapes fixed by the problem:
// B=4, S=1024, D=512, H=64, DK=8, FF=2048, NQ=8. Mtok = B*S = 4096.
// R10: multi-dispatch beats persistent mega-kernel.
// R12: bf16 intermediates. R13: wo_lnffn fusion (full-N 16-row blocks).
// R14: K-split-2 LDS-staged qkv/ffnout (-6us, best=146.3).
// R15: direct-frag GEMM REGRESSED +21 (scattered lines, no pipeline).
// R16: full-N ffnout REGRESSED +12 (W2 re-read 512MB: thin-M blocks only
// valid when W is tiny, e.g. Wo 0.5MB in wo_lnffn).
// R17: qkv/ffnout -> 2-wave cooperative core (the wo_lnffn-proven sync):
// wave0 stages A-tile, wave1 stages W-tile, shared ring-3 (48KB, depth-2
// prefetch), ONE s_barrier per K-step, counted per-wave vmcnt(8), full K
// per block (no K-split reduce), each wave owns a 64x32 N-half.
// 3 blocks/CU, 6 waves/CU; fixes R14's ring-2 latency exposure + reduce.

typedef short short8 __attribute__((ext_vector_type(8)));
typedef float floatx4 __attribute__((ext_vector_type(4)));

__device__ __forceinline__ unsigned short f2bf_bits(float f) {
  __hip_bfloat16 h = __float2bfloat16(f);
  return *reinterpret_cast<unsigned short*>(&h);
}
__device__ __forceinline__ float bfbits2f(unsigned short u) {
  union { unsigned int u; float f; } c;
  c.u = (unsigned int)u << 16;
  return c.f;
}

#define GLOBAL_LOAD_LDS16(g, l)                                               \
  __builtin_amdgcn_global_load_lds(                                           \
      (const __attribute__((address_space(1))) void*)(g),                     \
      (__attribute__((address_space(3))) void*)(l), 16, 0, 0)

// Compiler does NOT model global_load_lds's LDS write as aliasing later LDS
// reads. Explicit waits; memory clobber pins ordering around barriers.
#define WAIT_VMCNT0()   asm volatile("s_waitcnt vmcnt(0)" ::: "memory")
#define WAIT_VMCNT8()   asm volatile("s_waitcnt vmcnt(8)" ::: "memory")
#define WAIT_VMCNT10()  asm volatile("s_waitcnt vmcnt(10)" ::: "memory")
#define WAIT_LGKM0()    asm volatile("s_waitcnt lgkmcnt(0)" ::: "memory")
#define BARRIER()       __builtin_amdgcn_s_barrier()
#define CFENCE()        asm volatile("" ::: "memory")

// ---------------------------------------------------------------------------
// 2-wave cooperative GEMM core: acc_half(64x32) += A @ W^T over full K.
// Wave0 stages the 64x64 A-tile (8 loads), wave1 the 64x64 W-tile (8 loads)
// into the SHARED ring-3 slot (slot = A 8KB | W 8KB). Depth-2 prefetch:
// steady-state wait vmcnt(8) drains own tile-t loads; barrier publishes
// both waves' tiles. Stage t+2 -> slot (t-1)%3: all waves retired slot
// (t-1) reads (own lgkm0 at step t-1) before arriving at barrier t.
// XOR chunk swizzle as before: phys 16B chunk p of row r holds logical
// chunk p ^ (r&7) -> conflict-free ds_read_b128.
// ---------------------------------------------------------------------------
template<int NT>
__device__ __forceinline__ void gemm_coop2(
    const __hip_bfloat16* __restrict__ A,
    const __hip_bfloat16* __restrict__ W,
    int K, long m0, long n0, int wid, int lane,
    __hip_bfloat16* sh, floatx4 acc[4][2])
{
  const int srow = lane >> 3;
  const int gchunk = (lane & 7) ^ srow;
  const int frow = lane & 15;
  const int fk = lane >> 4;

  const __hip_bfloat16* src = wid ? W : A;
  const long r0 = wid ? n0 : m0;
  const int dstoff = wid ? 4096 : 0;

  auto stage = [&](int kt, int slot) {            // 8 loads, own operand
    __hip_bfloat16* buf = sh + slot * 8192 + dstoff;
#pragma unroll
    for (int ib = 0; ib < 8; ++ib) {
      const int row = ib * 8 + srow;
      GLOBAL_LOAD_LDS16(src + (r0 + row) * (long)K + kt + gchunk * 8,
                        buf + ib * 512);
    }
  };

  WAIT_LGKM0();                                   // prior LDS use retired
  stage(0, 0);
  stage(64, 1);

  for (int t = 0; t < NT; ++t) {
    const int slot = t % 3;
    if (t + 1 < NT) { WAIT_VMCNT8(); }            // drain own tile t
    else            { WAIT_VMCNT0(); }
    BARRIER();                                    // both tiles t visible

    __hip_bfloat16* buf = sh + slot * 8192;
    short8 af[2][4], bf[2][2];
#pragma unroll
    for (int ks = 0; ks < 2; ++ks) {
#pragma unroll
      for (int i = 0; i < 4; ++i) {
        const int ar = i * 16 + frow;
        af[ks][i] = *(const short8*)(buf + ar * 64 +
                                     (((ks * 4 + fk) ^ (ar & 7)) << 3));
      }
#pragma unroll
      for (int j = 0; j < 2; ++j) {
        const int wr = wid * 32 + j * 16 + frow;
        bf[ks][j] = *(const short8*)(buf + 4096 + wr * 64 +
                                     (((ks * 4 + fk) ^ (wr & 7)) << 3));
      }
    }
    WAIT_LGKM0();                       // frags in VGPR before slot reuse
    if (t + 2 < NT) stage((t + 2) << 6, (t + 2) % 3);
#pragma unroll
    for (int ks = 0; ks < 2; ++ks)
#pragma unroll
      for (int i = 0; i < 4; ++i)
#pragma unroll
        for (int j = 0; j < 2; ++j)
          acc[i][j] = __builtin_amdgcn_mfma_f32_16x16x32_bf16(
              af[ks][i], bf[ks][j], acc[i][j], 0, 0, 0);
  }
}

// half-width (64x32) store epilogues. D layout: row=(lane>>4)*4+reg,
// col=lane&15.
__device__ __forceinline__ void store_f32_half(
    floatx4 acc[4][2], float* __restrict__ C, const float* __restrict__ bias,
    long m0, long n0h, int lane)
{
  const int col_l = lane & 15;
  const int row_l = (lane >> 4) << 2;
#pragma unroll
  for (int j = 0; j < 2; ++j) {
    const long col = n0h + j * 16 + col_l;
    const float bv = bias[col];
#pragma unroll
    for (int i = 0; i < 4; ++i)
#pragma unroll
      for (int r = 0; r < 4; ++r)
        C[(m0 + i * 16 + row_l + r) * 512 + col] = acc[i][j][r] + bv;
  }
}

__device__ __forceinline__ void store_bf16_half(
    floatx4 acc[4][2], __hip_bfloat16* __restrict__ C,
    const float* __restrict__ bias, long m0, long n0h, int lane)
{
  const int col_l = lane & 15;
  const int row_l = (lane >> 4) << 2;
#pragma unroll
  for (int j = 0; j < 2; ++j) {
    const long col = n0h + j * 16 + col_l;
    const float bv = bias[col];
#pragma unroll
    for (int i = 0; i < 4; ++i)
#pragma unroll
      for (int r = 0; r < 4; ++r)
        C[(m0 + i * 16 + row_l + r) * 512 + col] =
            __float2bfloat16(acc[i][j][r] + bv);
  }
}

// ---------------------------------------------------------------------------
// QKV launch: grid (64, 8, 3) x 128 threads (2-wave cooperative, full K).
// z=0: Q = x@Wq^T+bq with fused quantum epilogue -> mix_bf; if *gateA != 1
// also writes Qb fp32. z=1/2: conditional K/V projections.
// ---------------------------------------------------------------------------
__global__ __launch_bounds__(128) void gemm_qkv(
    const __hip_bfloat16* __restrict__ x_bf,
    const __hip_bfloat16* __restrict__ Wq,
    const __hip_bfloat16* __restrict__ Wk,
    const __hip_bfloat16* __restrict__ Wv,
    const float* __restrict__ bq, const float* __restrict__ bk,
    const float* __restrict__ bvv,
    __hip_bfloat16* __restrict__ mix,
    float* __restrict__ Qb, float* __restrict__ Kb, float* __restrict__ Vb,
    const float* __restrict__ theta, const float* __restrict__ gateA)
{
  const int z = blockIdx.z;
  const float g = *gateA;
  if (z > 0 && g == 1.0f) return;
  const __hip_bfloat16* W = (z == 0) ? Wq : (z == 1) ? Wk : Wv;
  const float* bias = (z == 0) ? bq : (z == 1) ? bk : bvv;
  float* Cf = (z == 0) ? Qb : (z == 1) ? Kb : Vb;

  __shared__ __align__(16) __hip_bfloat16 sh[24576];   // 48 KB ring-3
  const int tid = threadIdx.x;
  const int wid = tid >> 6;
  const int lane = tid & 63;
  const long m0 = (long)blockIdx.x * 64;
  const long n0 = (long)blockIdx.y * 64;
  floatx4 acc[4][2];
#pragma unroll
  for (int i = 0; i < 4; ++i)
#pragma unroll
    for (int j = 0; j < 2; ++j) acc[i][j] = (floatx4){0.f, 0.f, 0.f, 0.f};

  gemm_coop2<8>(x_bf, W, 512, m0, n0, wid, lane, sh, acc);

  if (z > 0 || g != 1.0f)
    store_f32_half(acc, Cf, bias, m0, n0 + wid * 32, lane);

  if (z == 0) {
    // quantum epilogue: LDS-transpose acc(+bias) (each wave its N-half),
    // then per 8-wide head group o[0]=c1..c7, o[j>=1]=c0..cj with
    // c=cos(q+theta). Work split: wave w handles gidx rows [w*256, w*256+256).
    float* shf = (float*)sh;   // 64x64 fp32 = 16 KB (= ring slot 0)
    const int col_l = lane & 15;
    const int row_l = (lane >> 4) << 2;
    WAIT_LGKM0();
    CFENCE(); BARRIER(); CFENCE();   // all ring reads block-wide retired
#pragma unroll
    for (int j = 0; j < 2; ++j) {
      const int c = wid * 32 + j * 16 + col_l;
      const float bv = bias[n0 + c];
#pragma unroll
      for (int i = 0; i < 4; ++i)
#pragma unroll
        for (int r = 0; r < 4; ++r)
          shf[(i * 16 + row_l + r) * 64 + c] = acc[i][j][r] + bv;
    }
    WAIT_LGKM0();
    CFENCE(); BARRIER(); CFENCE();   // full 64x64 transpose visible
    float th[8];
#pragma unroll
    for (int i = 0; i < 8; ++i) th[i] = theta[i];
#pragma unroll
    for (int q = 0; q < 4; ++q) {
      const int gidx = (wid * 4 + q) * 64 + lane;
      const int row = gidx >> 3;
      const int hh = gidx & 7;
      const float* src = shf + row * 64 + hh * 8;
      float c[8];
#pragma unroll
      for (int i = 0; i < 8; ++i) c[i] = __cosf(src[i] + th[i]);
      float o[8];
      float p = c[1];
#pragma unroll
      for (int i = 2; i < 8; ++i) p *= c[i];
      o[0] = p;
      float cp = c[0];
#pragma unroll
      for (int i = 1; i < 8; ++i) { cp *= c[i]; o[i] = cp; }
      union { unsigned short u16[8]; uint4 v; } pk;
#pragma unroll
      for (int i = 0; i < 8; ++i) pk.u16[i] = f2bf_bits(o[i]);
      *(uint4*)(mix + (m0 + row) * 512 + n0 + hh * 8) = pk.v;
    }
  }
}

// ---------------------------------------------------------------------------
// R13 fused kernel: attn = mix @ Wo^T + bo ; x1 = LN1(x + attn) ;
// qm/xs -> hq (= relu(qm@W1^T+b1)) and cond hc. One block owns 16 rows x
// all 512 cols so the LN row-reduce is block-local.
// grid 256, blockDim 512 (8 waves). Wave w computes cols [64w, 64w+64).
// A-tile (16x64, 2KB) staged by wave0, SHARED by all waves; W-tile 64x64
// private per wave. A ring-3, W ring-2. Counted vmcnt per wave (wave0
// 10/iter = 2 A + 8 W; others 8) + raw s_barrier per K-step.
// LDS: A 3x2KB + W 8x2x8KB = 134KB -> 1 block/CU, 8 waves/CU.
// ---------------------------------------------------------------------------
__global__ __launch_bounds__(512) void wo_lnffn(
    const __hip_bfloat16* __restrict__ A,      // mix_bf [4096][512]
    const __hip_bfloat16* __restrict__ W,      // Wo_bf  [512][512]
    const float* __restrict__ bo,
    const float* __restrict__ x,
    const float* __restrict__ lw, const float* __restrict__ lb,
    float* __restrict__ x1, const float* __restrict__ phi,
    const float* __restrict__ W1,              // fp32 [2048][8]
    const float* __restrict__ b1,
    __hip_bfloat16* __restrict__ hq, __hip_bfloat16* __restrict__ hc,
    const float* __restrict__ gateF)
{
  __shared__ __align__(16) __hip_bfloat16 sh[68608];   // 134 KB
  const int tid = threadIdx.x;
  const int wid = tid >> 6;
  const int lane = tid & 63;
  const long m0 = (long)blockIdx.x * 16;
  const long n0w = (long)wid * 64;

  const int srow = lane >> 3;               // 0..7
  const int gchunk = (lane & 7) ^ srow;     // pre-swizzled global source
  const int frow = lane & 15;
  const int fk = lane >> 4;                 // 0..3

  __hip_bfloat16* shA = sh;                       // 3 slots x 1024 bf16
  __hip_bfloat16* shW = sh + 3072 + wid * 8192;   // 2 slots x 4096 bf16

  auto stageA = [&](int kt, int slot) {           // wave 0 only; 2 instrs
    __hip_bfloat16* buf = shA + slot * 1024;
#pragma unroll
    for (int i = 0; i < 2; ++i) {
      const int row = i * 8 + srow;               // 0..15
      GLOBAL_LOAD_LDS16(A + (m0 + row) * 512 + kt + gchunk * 8, buf + i * 512);
    }
  };
  auto stageW = [&](int kt, int slot) {           // 8 instrs
    __hip_bfloat16* buf = shW + slot * 4096;
#pragma unroll
    for (int i = 0; i < 8; ++i) {
      const int row = i * 8 + srow;
      GLOBAL_LOAD_LDS16(W + (n0w + row) * 512 + kt + gchunk * 8, buf + i * 512);
    }
  };

  floatx4 acc[4];
#pragma unroll
  for (int j = 0; j < 4; ++j) acc[j] = (floatx4){0.f, 0.f, 0.f, 0.f};

  // Prologue: wave0 issue order A0,W0,A1,W1 so vmcnt(10) leaves {A1,W1}.
  if (wid == 0) stageA(0, 0);
  stageW(0, 0);
  if (wid == 0) stageA(64, 1);
  stageW(64, 1);

  for (int t = 0; t < 8; ++t) {
    const int wslot = t & 1;
    const int aslot = t % 3;
    if (t < 7) { if (wid == 0) WAIT_VMCNT10(); else WAIT_VMCNT8(); }
    else       { WAIT_VMCNT0(); }
    // wave0 passed its wait => A(t) landed; barrier publishes it to all.
    BARRIER();

    short8 af[2], bf[2][4];
#pragma unroll
    for (int ks = 0; ks < 2; ++ks) {
      af[ks] = *(const short8*)(shA + aslot * 1024 + frow * 64 +
                                (((ks * 4 + fk) ^ (frow & 7)) << 3));
#pragma unroll
      for (int j = 0; j < 4; ++j) {
        const int wr = j * 16 + frow;
        bf[ks][j] = *(const short8*)(shW + wslot * 4096 + wr * 64 +
                                     (((ks * 4 + fk) ^ (wr & 7)) << 3));
      }
    }
    WAIT_LGKM0();                       // frags in VGPR before slot reuse
    if (t < 6) {
      // A(t+2) -> slot (t+2)%3 == (t-1)%3: every wave retired its reads of
      // tile t-1 before reaching this iteration's barrier. W slot private.
      if (wid == 0) stageA((t + 2) << 6, (t + 2) % 3);
      stageW((t + 2) << 6, wslot);
    }
#pragma unroll
    for (int ks = 0; ks < 2; ++ks)
#pragma unroll
      for (int j = 0; j < 4; ++j)
        acc[j] = __builtin_amdgcn_mfma_f32_16x16x32_bf16(
            af[ks], bf[ks][j], acc[j], 0, 0, 0);
  }

  // All waves completed frag reads (own lgkm0 at t=7) before this barrier;
  // attnL (33KB) overlaps shA + shW of waves 0/1 -> barrier REQUIRED.
  BARRIER();

  float* attnL = (float*)sh;            // [16][516] fp32 (pad 516: 2-way max)
  float* qmL = attnL + 16 * 516;        // [16][8]
  float* xsL = qmL + 128;               // [16][8]
  {
    const int col_l = lane & 15;
    const int row_l = (lane >> 4) << 2;
#pragma unroll
    for (int j = 0; j < 4; ++j) {
      const int c = (int)n0w + j * 16 + col_l;
      const float bv = bo[c];
#pragma unroll
      for (int r = 0; r < 4; ++r)
        attnL[(row_l + r) * 516 + c] = acc[j][r] + bv;
    }
  }
  WAIT_LGKM0();
  BARRIER();

  // LN1 over 512 cols: 32 threads per row, shfl-xor reduce within width 32.
  const int rr = tid >> 5;              // 0..15
  const int cl = tid & 31;
  const long rowg = m0 + rr;
  float sv[16];
  float sum = 0.f, ssq = 0.f;
#pragma unroll
  for (int i = 0; i < 16; ++i) {
    const int c = cl + i * 32;
    const float v = x[rowg * 512 + c] + attnL[rr * 516 + c];
    sv[i] = v; sum += v; ssq += v * v;
  }
#pragma unroll
  for (int off = 16; off > 0; off >>= 1) {
    sum += __shfl_xor(sum, off, 32);
    ssq += __shfl_xor(ssq, off, 32);
  }
  const float mean = sum * (1.0f / 512.0f);
  const float var = ssq * (1.0f / 512.0f) - mean * mean;
  const float rstd = rsqrtf(fmaxf(var, 0.0f) + 1e-5f);
#pragma unroll
  for (int i = 0; i < 16; ++i) {
    const int c = cl + i * 32;
    const float o = (sv[i] - mean) * rstd * lw[c] + lb[c];
    x1[rowg * 512 + c] = o;
    if (i == 0 && cl < 8) {
      qmL[rr * 8 + cl] = __cosf(o) * __cosf(phi[cl]);
      xsL[rr * 8 + cl] = o;
    }
  }
  WAIT_LGKM0();
  BARRIER();

  // FFN-h: thread owns outputs n = tid*4 .. tid*4+3 for all 16 rows.
  const int n4 = tid << 2;
  float w1r[4][8];
#pragma unroll
  for (int jr = 0; jr < 4; ++jr) {
    float4 wa = *(const float4*)(W1 + (long)(n4 + jr) * 8);
    float4 wb = *(const float4*)(W1 + (long)(n4 + jr) * 8 + 4);
    w1r[jr][0] = wa.x; w1r[jr][1] = wa.y; w1r[jr][2] = wa.z; w1r[jr][3] = wa.w;
    w1r[jr][4] = wb.x; w1r[jr][5] = wb.y; w1r[jr][6] = wb.z; w1r[jr][7] = wb.w;
  }
  float4 bb = *(const float4*)(b1 + n4);
  const float b1a[4] = {bb.x, bb.y, bb.z, bb.w};
  const float gv = *gateF;
#pragma unroll 2
  for (int r = 0; r < 16; ++r) {
    float qm8[8];
#pragma unroll
    for (int k = 0; k < 8; ++k) qm8[k] = qmL[r * 8 + k];   // LDS broadcast
    union { unsigned short u16[4]; ushort4 v; } pk;
#pragma unroll
    for (int jr = 0; jr < 4; ++jr) {
      float a = b1a[jr];
#pragma unroll
      for (int k = 0; k < 8; ++k) a += qm8[k] * w1r[jr][k];
      pk.u16[jr] = f2bf_bits(fmaxf(a, 0.0f));
    }
    *(ushort4*)(hq + (m0 + r) * 2048 + n4) = pk.v;
    if (gv != 1.0f) {
      float xs8[8];
#pragma unroll
      for (int k = 0; k < 8; ++k) xs8[k] = xsL[r * 8 + k];
#pragma unroll
      for (int jr = 0; jr < 4; ++jr) {
        float a = b1a[jr];
#pragma unroll
        for (int k = 0; k < 8; ++k) a += xs8[k] * w1r[jr][k];
        pk.u16[jr] = f2bf_bits(fmaxf(a, 0.0f));
      }
      *(ushort4*)(hc + (m0 + r) * 2048 + n4) = pk.v;
    }
  }
}

// ---------------------------------------------------------------------------
// FFN-out: grid (64, 8, 2) x 128 threads (2-wave cooperative, K=2048, 32
// steps). z=0: Fb = hq@W2^T+b2 (bf16). z=1 (cond gateF!=1): Fc = hc@W2^T+b2.
// ---------------------------------------------------------------------------
__global__ __launch_bounds__(128) void gemm_ffnout(
    const __hip_bfloat16* __restrict__ hq,
    const __hip_bfloat16* __restrict__ hc,
    const __hip_bfloat16* __restrict__ W2, const float* __restrict__ b2,
    __hip_bfloat16* __restrict__ Fb, __hip_bfloat16* __restrict__ Fc,
    const float* __restrict__ gateF)
{
  const int z = blockIdx.z;
  if (z == 1 && *gateF == 1.0f) return;
  const __hip_bfloat16* A = z ? hc : hq;
  __hip_bfloat16* C = z ? Fc : Fb;
  __shared__ __align__(16) __hip_bfloat16 sh[24576];   // 48 KB ring-3
  const int tid = threadIdx.x;
  const int wid = tid >> 6;
  const int lane = tid & 63;
  const long m0 = (long)blockIdx.x * 64;
  const long n0 = (long)blockIdx.y * 64;
  floatx4 acc[4][2];
#pragma unroll
  for (int i = 0; i < 4; ++i)
#pragma unroll
    for (int j = 0; j < 2; ++j) acc[i][j] = (floatx4){0.f, 0.f, 0.f, 0.f};
  gemm_coop2<32>(A, W2, 2048, m0, n0, wid, lane, sh, acc);
  store_bf16_half(acc, C, b2, m0, n0 + wid * 32, lane);
}

// ---------------------------------------------------------------------------
// input prep: fp32->bf16 for x, Wq, Wo, W2; conditional Wk/Wv.
// (W1 stays fp32 — consumed directly by wo_lnffn.)
// ---------------------------------------------------------------------------
__device__ __forceinline__ void cvt_one(const float* s, __hip_bfloat16* d, int n,
                                        long tid, long stride) {
  const int n4 = n >> 2;
  for (long i = tid; i < n4; i += stride) {
    float4 v = ((const float4*)s)[i];
    ushort4 u;
    u.x = f2bf_bits(v.x); u.y = f2bf_bits(v.y);
    u.z = f2bf_bits(v.z); u.w = f2bf_bits(v.w);
    ((ushort4*)d)[i] = u;
  }
}

__global__ __launch_bounds__(256) void prep_inputs(
    const float* x, __hip_bfloat16* x_bf,
    const float* Wq, __hip_bfloat16* Wq_bf,
    const float* Wo, __hip_bfloat16* Wo_bf,
    const float* W2, __hip_bfloat16* W2_bf,
    const float* Wk, __hip_bfloat16* Wk_bf,
    const float* Wv, __hip_bfloat16* Wv_bf,
    const float* gateA)
{
  const long stride = (long)gridDim.x * blockDim.x;
  const long tid = (long)blockIdx.x * blockDim.x + threadIdx.x;
  cvt_one(x, x_bf, 4096 * 512, tid, stride);
  cvt_one(Wq, Wq_bf, 512 * 512, tid, stride);
  cvt_one(Wo, Wo_bf, 512 * 512, tid, stride);
  cvt_one(W2, W2_bf, 512 * 2048, tid, stride);
  if (*gateA != 1.0f) {
    cvt_one(Wk, Wk_bf, 512 * 512, tid, stride);
    cvt_one(Wv, Wv_bf, 512 * 512, tid, stride);
  }
}

// ---------------------------------------------------------------------------
// [cond gateA!=1] classical softmax attention + blend into mix (bf16).
// ---------------------------------------------------------------------------
__global__ __launch_bounds__(256) void attn_blend(
    const float* __restrict__ Qb, const float* __restrict__ Kb,
    const float* __restrict__ Vb, __hip_bfloat16* __restrict__ mix,
    const float* __restrict__ gateA)
{
  const float g = *gateA;
  if (g == 1.0f) return;
  const int idx = blockIdx.x * blockDim.x + threadIdx.x;
  if (idx >= 4 * 64 * 1024) return;
  const int s = idx & 1023;
  const int h = (idx >> 10) & 63;
  const int b = idx >> 16;
  const long qoff = ((long)(b * 1024 + s)) * 512 + h * 8;
  float q[8];
#pragma unroll
  for (int i = 0; i < 8; ++i) q[i] = Qb[qoff + i] * 0.35355339059327373f;
  float m = -INFINITY, l = 0.0f, acc[8];
#pragma unroll
  for (int i = 0; i < 8; ++i) acc[i] = 0.0f;
  for (int t = 0; t < 1024; ++t) {
    const long koff = ((long)(b * 1024 + t)) * 512 + h * 8;
    const float* kr = Kb + koff;
    const float* vr = Vb + koff;
    float sc = 0.0f;
#pragma unroll
    for (int i = 0; i < 8; ++i) sc += q[i] * kr[i];
    float nm = fmaxf(m, sc);
    float corr = __expf(m - nm);
    float p = __expf(sc - nm);
    l = l * corr + p;
#pragma unroll
    for (int i = 0; i < 8; ++i) acc[i] = acc[i] * corr + p * vr[i];
    m = nm;
  }
  const float inv = 1.0f / l;
  union { unsigned short u16[8]; uint4 v; } pk;
  pk.v = *(const uint4*)(mix + qoff);
#pragma unroll
  for (int i = 0; i < 8; ++i) {
    float quant = bfbits2f(pk.u16[i]);
    pk.u16[i] = f2bf_bits(g * quant + (1.0f - g) * acc[i] * inv);
  }
  *(uint4*)(mix + qoff) = pk.v;
}

// ---------------------------------------------------------------------------
// Final LN: out = LN(x1 + mix(Fb, Fc; gateF)), Fb/Fc bf16 (R12).
// Wave-per-row, 4 rows/block, no barriers. grid 1024.
// ---------------------------------------------------------------------------
__global__ __launch_bounds__(256) void add_ln3(
    const float* __restrict__ x1, const __hip_bfloat16* __restrict__ Fb,
    const __hip_bfloat16* __restrict__ Fc, const float* __restrict__ gateF,
    const float* __restrict__ lw, const float* __restrict__ lb,
    float* __restrict__ out)
{
  const int tid = threadIdx.x;
  const int wv = tid >> 6, lane = tid & 63;
  const int row = blockIdx.x * 4 + wv;
  const long base = (long)row * 512;
  const int c0 = lane * 8;
  float4 a0 = *(const float4*)(x1 + base + c0);
  float4 a1 = *(const float4*)(x1 + base + c0 + 4);
  union { unsigned short u16[8]; uint4 v; } fb;
  fb.v = *(const uint4*)(Fb + base + c0);
  const float xa[8] = {a0.x, a0.y, a0.z, a0.w, a1.x, a1.y, a1.z, a1.w};
  float s[8];
  const float gv = *gateF;
  if (gv != 1.0f) {
    union { unsigned short u16[8]; uint4 v; } fc;
    fc.v = *(const uint4*)(Fc + base + c0);
    const float om = 1.0f - gv;
#pragma unroll
    for (int i = 0; i < 8; ++i)
      s[i] = xa[i] + gv * bfbits2f(fb.u16[i]) + om * bfbits2f(fc.u16[i]);
  } else {
#pragma unroll
    for (int i = 0; i < 8; ++i) s[i] = xa[i] + bfbits2f(fb.u16[i]);
  }
  float sum = 0.f, ssq = 0.f;
#pragma unroll
  for (int i = 0; i < 8; ++i) { sum += s[i]; ssq += s[i] * s[i]; }
#pragma unroll
  for (int off = 32; off > 0; off >>= 1) {
    sum += __shfl_xor(sum, off);
    ssq += __shfl_xor(ssq, off);
  }
  const float mean = sum * (1.0f / 512.0f);
  const float var = ssq * (1.0f / 512.0f) - mean * mean;
  const float rstd = rsqrtf(fmaxf(var, 0.0f) + 1e-5f);
  float4 w0 = *(const float4*)(lw + c0);
  float4 w1 = *(const float4*)(lw + c0 + 4);
  float4 g0 = *(const float4*)(lb + c0);
  float4 g1 = *(const float4*)(lb + c0 + 4);
  const float wf[8] = {w0.x, w0.y, w0.z, w0.w, w1.x, w1.y, w1.z, w1.w};
  const float gf8[8] = {g0.x, g0.y, g0.z, g0.w, g1.x, g1.y, g1.z, g1.w};
  float o[8];
#pragma unroll
  for (int i = 0; i < 8; ++i) o[i] = (s[i] - mean) * rstd * wf[i] + gf8[i];
  *(float4*)(out + base + c0) = (float4){o[0], o[1], o[2], o[3]};
  *(float4*)(out + base + c0 + 4) = (float4){o[4], o[5], o[6], o[7]};
}

// ---------------------------------------------------------------------------
extern "C" void kernel_launch(void* const* d_in, const int* in_sizes, int n_in,
                              void* d_out, int out_size, void* d_ws, size_t ws_size,
                              hipStream_t stream) {
  const float* x     = (const float*)d_in[0];
  const float* Wq    = (const float*)d_in[1];
  const float* bq    = (const float*)d_in[2];
  const float* Wk    = (const float*)d_in[3];
  const float* bk    = (const float*)d_in[4];
  const float* Wv    = (const float*)d_in[5];
  const float* bv    = (const float*)d_in[6];
  const float* theta = (const float*)d_in[7];
  const float* gateA = (const float*)d_in[8];
  const float* Wo    = (const float*)d_in[9];
  const float* bo    = (const float*)d_in[10];
  const float* ln1w  = (const float*)d_in[11];
  const float* ln1b  = (const float*)d_in[12];
  const float* W1    = (const float*)d_in[13];
  const float* b1    = (const float*)d_in[14];
  const float* W2    = (const float*)d_in[15];
  const float* b2    = (const float*)d_in[16];
  const float* phi   = (const float*)d_in[17];
  const float* gateF = (const float*)d_in[18];
  const float* ln2w  = (const float*)d_in[19];
  const float* ln2b  = (const float*)d_in[20];
  float* out = (float*)d_out;

  const size_t MB = 1024 * 1024;
  char* wsb = (char*)d_ws;
  __hip_bfloat16* x_bf    = (__hip_bfloat16*)(wsb + 0 * MB);            // 4 MB
  __hip_bfloat16* Wq_bf   = (__hip_bfloat16*)(wsb + 4 * MB);            // 0.5 MB
  __hip_bfloat16* Wo_bf   = (__hip_bfloat16*)(wsb + 4 * MB + 512 * 1024);
  __hip_bfloat16* W2_bf   = (__hip_bfloat16*)(wsb + 5 * MB);            // 2 MB
  __hip_bfloat16* mix_bf  = (__hip_bfloat16*)(wsb + 8 * MB);            // 4 MB
  float*          x1      = (float*)(wsb + 16 * MB);                    // 8 MB
  __hip_bfloat16* hq_bf   = (__hip_bfloat16*)(wsb + 24 * MB);           // 16 MB
  __hip_bfloat16* Fb_bf   = (__hip_bfloat16*)(wsb + 40 * MB);           // 4 MB
  // conditional (gate != 1) buffers
  float*          Qb      = (float*)(wsb + 52 * MB);                    // 8 MB
  __hip_bfloat16* Wk_bf   = (__hip_bfloat16*)(wsb + 60 * MB);
  __hip_bfloat16* Wv_bf   = (__hip_bfloat16*)(wsb + 60 * MB + 512 * 1024);
  float*          Kb2     = (float*)(wsb + 61 * MB);                    // 8 MB
  float*          Vb2     = (float*)(wsb + 69 * MB);                    // 8 MB
  __hip_bfloat16* hc_bf   = (__hip_bfloat16*)(wsb + 77 * MB);           // 16 MB
  __hip_bfloat16* Fc_bf   = (__hip_bfloat16*)(wsb + 93 * MB);           // 4 MB

  // 1. input prep (all conversions; W1 stays fp32)
  prep_inputs<<<1024, 256, 0, stream>>>(
      x, x_bf, Wq, Wq_bf, Wo, Wo_bf, W2, W2_bf, Wk, Wk_bf, Wv, Wv_bf, gateA);
  // 2. QKV: z=0 Q+quantum -> mix_bf (+Qb cond); z=1/2 K/V (cond)
  gemm_qkv<<<dim3(64, 8, 3), 128, 0, stream>>>(
      x_bf, Wq_bf, Wk_bf, Wv_bf, bq, bk, bv,
      mix_bf, Qb, Kb2, Vb2, theta, gateA);
  // 3. [cond] classical attention + blend into mix_bf
  attn_blend<<<1024, 256, 0, stream>>>(Qb, Kb2, Vb2, mix_bf, gateA);
  // 4. R13 fused: attn = mix@Wo^T+bo ; x1 = LN1(x+attn) ; hq (+hc cond)
  wo_lnffn<<<256, 512, 0, stream>>>(
      mix_bf, Wo_bf, bo, x, ln1w, ln1b, x1, phi, W1, b1, hq_bf, hc_bf, gateF);
  // 5. Fb = hq @ W2^T + b2 (z=0); Fc = hc @ W2^T + b2 (z=1, cond), bf16
  gemm_ffnout<<<dim3(64, 8, 2), 128, 0, stream>>>(
      hq_bf, hc_bf, W2_bf, b2, Fb_bf, Fc_bf, gateF);
  // 6. out = LN(x1 + gF*Fb + (1-gF)*Fc)
  add_ln3<<<1024, 256, 0, stream>>>(x1, Fb_bf, Fc_bf, gateF, ln2w, ln2b, out);
}

// Round 6
// 148.741 us; speedup vs baseline: 1.1289x; 1.0052x over previous
//
#include <hip/hip_runtime.h>
#include <hip/hip_bf16.h>

// Shapes fixed by the problem:
// B=4, S=1024, D=512, H=64, DK=8, FF=2048, NQ=8. Mtok = B*S = 4096.
// R10: multi-dispatch beats persistent mega-kernel.
// R12: bf16 intermediates. R13: wo_lnffn fusion.
// R14: K-split-2 LDS-staged qkv/ffnout = BEST 146.3.
// R15: direct-frag GEMM +21 (regressed). R16: full-N ffnout +12 (regressed).
// R17: coop-2 +3 (sideways: 3 indep streams/CU vs R14's 4).
// R18: occupancy ladder: R11(3 streams)=155 -> R14(4)=146 is the only
// monotone signal; all variants <=1 wave/SIMD. qkv -> 32x32 single-wave
// tiles: ring-2 = 16 KB -> 10 blocks/CU = 2.5 waves/SIMD (TLP hides the
// per-step vmcnt stall, m114 mechanism). n-inner grid: consecutive blocks
// share the A-slice; x_bf+Wq are L2-resident so re-reads are cheap.
// ffnout reverted to R14's exact K-split-2 core.

typedef short short8 __attribute__((ext_vector_type(8)));
typedef float floatx4 __attribute__((ext_vector_type(4)));

__device__ __forceinline__ unsigned short f2bf_bits(float f) {
  __hip_bfloat16 h = __float2bfloat16(f);
  return *reinterpret_cast<unsigned short*>(&h);
}
__device__ __forceinline__ float bfbits2f(unsigned short u) {
  union { unsigned int u; float f; } c;
  c.u = (unsigned int)u << 16;
  return c.f;
}

#define GLOBAL_LOAD_LDS16(g, l)                                               \
  __builtin_amdgcn_global_load_lds(                                           \
      (const __attribute__((address_space(1))) void*)(g),                     \
      (__attribute__((address_space(3))) void*)(l), 16, 0, 0)

// Compiler does NOT model global_load_lds's LDS write as aliasing later LDS
// reads. Explicit waits; memory clobber pins ordering.
#define WAIT_VMCNT0()   asm volatile("s_waitcnt vmcnt(0)" ::: "memory")
#define WAIT_VMCNT8()   asm volatile("s_waitcnt vmcnt(8)" ::: "memory")
#define WAIT_VMCNT10()  asm volatile("s_waitcnt vmcnt(10)" ::: "memory")
#define WAIT_VMCNT16()  asm volatile("s_waitcnt vmcnt(16)" ::: "memory")
#define WAIT_LGKM0()    asm volatile("s_waitcnt lgkmcnt(0)" ::: "memory")
#define BARRIER()       __builtin_amdgcn_s_barrier()
#define CFENCE()        asm volatile("" ::: "memory")

// ---------------------------------------------------------------------------
// Per-wave GEMM core over a K-range, ring-2 staging (32 KB / wave):
// acc(64x64) += A[:, kr] @ W[:, kr]^T. 4x4 of 16x16x32 MFMA, BK=64.
// XOR chunk swizzle: phys 16B chunk p of row r holds logical chunk
// p ^ (r&7) -> conflict-free ds_read_b128. (R14 core, unchanged.)
// ---------------------------------------------------------------------------
__device__ __forceinline__ void gemm_core_ks(
    const __hip_bfloat16* __restrict__ A,
    const __hip_bfloat16* __restrict__ W,
    int K, int kbeg, int ntiles, long m0, long n0, int lane,
    __hip_bfloat16* sh, floatx4 acc[4][4])
{
  const int srow = lane >> 3;
  const int gchunk = (lane & 7) ^ srow;
  const int frow = lane & 15;
  const int fk = lane >> 4;

  auto stage = [&](int kt, __hip_bfloat16* buf) {
#pragma unroll
    for (int ib = 0; ib < 8; ++ib) {
      const int row = ib * 8 + srow;
      GLOBAL_LOAD_LDS16(A + (m0 + row) * K + kt + gchunk * 8, buf + ib * 512);
      GLOBAL_LOAD_LDS16(W + (n0 + row) * K + kt + gchunk * 8, buf + 4096 + ib * 512);
    }
  };

  WAIT_LGKM0();                         // prior LDS reads retired
  stage(kbeg, sh);
  if (ntiles > 1) stage(kbeg + 64, sh + 8192);

  for (int t = 0; t < ntiles; ++t) {
    __hip_bfloat16* buf = sh + (t & 1) * 8192;
    if (t < ntiles - 1) { WAIT_VMCNT16(); }   // current tile landed
    else               { WAIT_VMCNT0(); }

    short8 af[2][4], bf[2][4];
#pragma unroll
    for (int ks = 0; ks < 2; ++ks)
#pragma unroll
      for (int i = 0; i < 4; ++i) {
        const int ar = i * 16 + frow;
        af[ks][i] = *(const short8*)(buf + ar * 64 + (((ks * 4 + fk) ^ (ar & 7)) << 3));
        bf[ks][i] = *(const short8*)(buf + 4096 + ar * 64 + (((ks * 4 + fk) ^ (ar & 7)) << 3));
      }
    WAIT_LGKM0();                       // frags in VGPR before buf reuse
    if (t + 2 < ntiles) stage(kbeg + ((t + 2) << 6), buf);
#pragma unroll
    for (int ks = 0; ks < 2; ++ks)
#pragma unroll
      for (int i = 0; i < 4; ++i)
#pragma unroll
        for (int j = 0; j < 4; ++j)
          acc[i][j] = __builtin_amdgcn_mfma_f32_16x16x32_bf16(
              af[ks][i], bf[ks][j], acc[i][j], 0, 0, 0);
  }
}

// K-split reduce: wave1 dumps acc into its own ring slot 0 (16 KB fp32),
// wave0 adds. Returns true for the wave that continues (wave0).
__device__ __forceinline__ bool ks_reduce(
    floatx4 acc[4][4], __hip_bfloat16* sh, int wid, int lane)
{
  float* red = (float*)(sh + 16384);    // wave1 ring, slot 0
  if (wid == 1) {
#pragma unroll
    for (int i = 0; i < 4; ++i)
#pragma unroll
      for (int j = 0; j < 4; ++j)
        *(floatx4*)(red + ((i * 4 + j) * 64 + lane) * 4) = acc[i][j];
    WAIT_LGKM0();
  }
  CFENCE(); BARRIER(); CFENCE();
  if (wid == 1) return false;
#pragma unroll
  for (int i = 0; i < 4; ++i)
#pragma unroll
    for (int j = 0; j < 4; ++j)
      acc[i][j] += *(const floatx4*)(red + ((i * 4 + j) * 64 + lane) * 4);
  return true;
}

// bf16 store epilogue (64x64). D layout: row=(lane>>4)*4+reg, col=lane&15.
__device__ __forceinline__ void store_bf16(
    floatx4 acc[4][4], __hip_bfloat16* __restrict__ C,
    const float* __restrict__ bias, long m0, long n0, int lane)
{
  const int col_l = lane & 15;
  const int row_l = (lane >> 4) << 2;
#pragma unroll
  for (int j = 0; j < 4; ++j) {
    const long col = n0 + j * 16 + col_l;
    const float bv = bias[col];
#pragma unroll
    for (int i = 0; i < 4; ++i)
#pragma unroll
      for (int r = 0; r < 4; ++r)
        C[(m0 + i * 16 + row_l + r) * 512 + col] =
            __float2bfloat16(acc[i][j][r] + bv);
  }
}

// ---------------------------------------------------------------------------
// R18 QKV: 32x32 single-wave tiles. grid (16, 128, 3) x 64 threads
// (n-inner: consecutive blocks share the A-slice). Ring-2 = 16 KB ->
// 10 blocks/CU = 2.5 waves/SIMD. Per K-step: 8 global_load_lds (4 A + 4 W),
// wait vmcnt(8) (tile t drained, t+1 in flight), 8 ds_read_b128, 8 MFMA.
// z=0: Q + quantum epilogue -> mix_bf (+Qb fp32 cond). z=1/2: cond K/V.
// ---------------------------------------------------------------------------
__global__ __launch_bounds__(64) void gemm_qkv(
    const __hip_bfloat16* __restrict__ x_bf,
    const __hip_bfloat16* __restrict__ Wq,
    const __hip_bfloat16* __restrict__ Wk,
    const __hip_bfloat16* __restrict__ Wv,
    const float* __restrict__ bq, const float* __restrict__ bk,
    const float* __restrict__ bvv,
    __hip_bfloat16* __restrict__ mix,
    float* __restrict__ Qb, float* __restrict__ Kb, float* __restrict__ Vb,
    const float* __restrict__ theta, const float* __restrict__ gateA)
{
  const int z = blockIdx.z;
  const float g = *gateA;
  if (z > 0 && g == 1.0f) return;
  const __hip_bfloat16* W = (z == 0) ? Wq : (z == 1) ? Wk : Wv;
  const float* bias = (z == 0) ? bq : (z == 1) ? bk : bvv;
  float* Cf = (z == 0) ? Qb : (z == 1) ? Kb : Vb;

  __shared__ __align__(16) __hip_bfloat16 sh[8192];   // 16 KB: ring-2
  const int lane = threadIdx.x;
  const long n0 = (long)blockIdx.x * 32;    // 16 n-strips (inner)
  const long m0 = (long)blockIdx.y * 32;    // 128 m-strips
  const int srow = lane >> 3;
  const int gchunk = (lane & 7) ^ srow;
  const int frow = lane & 15;
  const int fk = lane >> 4;

  auto stage = [&](int kt, int slot) {      // 8 loads: 4 A + 4 W
    __hip_bfloat16* buf = sh + slot * 4096;
#pragma unroll
    for (int ib = 0; ib < 4; ++ib) {
      const int row = ib * 8 + srow;
      GLOBAL_LOAD_LDS16(x_bf + (m0 + row) * 512 + kt + gchunk * 8,
                        buf + ib * 512);
      GLOBAL_LOAD_LDS16(W + (n0 + row) * 512 + kt + gchunk * 8,
                        buf + 2048 + ib * 512);
    }
  };

  floatx4 acc[2][2];
#pragma unroll
  for (int i = 0; i < 2; ++i)
#pragma unroll
    for (int j = 0; j < 2; ++j) acc[i][j] = (floatx4){0.f, 0.f, 0.f, 0.f};

  stage(0, 0);
  stage(64, 1);

  for (int t = 0; t < 8; ++t) {
    __hip_bfloat16* buf = sh + (t & 1) * 4096;
    if (t < 7) { WAIT_VMCNT8(); }       // tile t drained, t+1 in flight
    else       { WAIT_VMCNT0(); }

    short8 af[2][2], bf[2][2];
#pragma unroll
    for (int ks = 0; ks < 2; ++ks)
#pragma unroll
      for (int i = 0; i < 2; ++i) {
        const int ar = i * 16 + frow;
        af[ks][i] = *(const short8*)(buf + ar * 64 +
                                     (((ks * 4 + fk) ^ (ar & 7)) << 3));
        bf[ks][i] = *(const short8*)(buf + 2048 + ar * 64 +
                                     (((ks * 4 + fk) ^ (ar & 7)) << 3));
      }
    WAIT_LGKM0();                       // frags in VGPR before slot reuse
    if (t + 2 < 8) stage((t + 2) << 6, t & 1);
#pragma unroll
    for (int ks = 0; ks < 2; ++ks)
#pragma unroll
      for (int i = 0; i < 2; ++i)
#pragma unroll
        for (int j = 0; j < 2; ++j)
          acc[i][j] = __builtin_amdgcn_mfma_f32_16x16x32_bf16(
              af[ks][i], bf[ks][j], acc[i][j], 0, 0, 0);
  }

  const int col_l = lane & 15;
  const int row_l = (lane >> 4) << 2;

  if (z > 0 || g != 1.0f) {             // fp32 store (32x32)
#pragma unroll
    for (int j = 0; j < 2; ++j) {
      const long col = n0 + j * 16 + col_l;
      const float bv = bias[col];
#pragma unroll
      for (int i = 0; i < 2; ++i)
#pragma unroll
        for (int r = 0; r < 4; ++r)
          Cf[(m0 + i * 16 + row_l + r) * 512 + col] = acc[i][j][r] + bv;
    }
  }
  if (z == 0) {
    // quantum epilogue: LDS-transpose acc(+bias) (32x32 fp32 = 4 KB), then
    // per 8-wide head group o[0]=c1..c7, o[j>=1]=c0..cj, c=cos(q+theta).
    // Single wave: in-order DS pipe; lgkm fences pin ordering/completion.
    float* shf = (float*)sh;
    WAIT_LGKM0();
#pragma unroll
    for (int j = 0; j < 2; ++j) {
      const int c = j * 16 + col_l;
      const float bv = bias[n0 + c];
#pragma unroll
      for (int i = 0; i < 2; ++i)
#pragma unroll
        for (int r = 0; r < 4; ++r)
          shf[(i * 16 + row_l + r) * 32 + c] = acc[i][j][r] + bv;
    }
    WAIT_LGKM0();
    float th[8];
#pragma unroll
    for (int i = 0; i < 8; ++i) th[i] = theta[i];
#pragma unroll
    for (int q = 0; q < 2; ++q) {
      const int gidx = q * 64 + lane;   // 0..127 = 32 rows x 4 heads
      const int row = gidx >> 2;
      const int hh = gidx & 3;
      const float* src = shf + row * 32 + hh * 8;
      float c[8];
#pragma unroll
      for (int i = 0; i < 8; ++i) c[i] = __cosf(src[i] + th[i]);
      float o[8];
      float p = c[1];
#pragma unroll
      for (int i = 2; i < 8; ++i) p *= c[i];
      o[0] = p;
      float cp = c[0];
#pragma unroll
      for (int i = 1; i < 8; ++i) { cp *= c[i]; o[i] = cp; }
      union { unsigned short u16[8]; uint4 v; } pk;
#pragma unroll
      for (int i = 0; i < 8; ++i) pk.u16[i] = f2bf_bits(o[i]);
      *(uint4*)(mix + (m0 + row) * 512 + n0 + hh * 8) = pk.v;
    }
  }
}

// ---------------------------------------------------------------------------
// R13 fused kernel: attn = mix @ Wo^T + bo ; x1 = LN1(x + attn) ;
// qm/xs -> hq (= relu(qm@W1^T+b1)) and cond hc. One block owns 16 rows x
// all 512 cols so the LN row-reduce is block-local.
// grid 256, blockDim 512 (8 waves). Wave w computes cols [64w, 64w+64).
// A-tile staged by wave0, SHARED; W-tile private per wave. A ring-3, W
// ring-2. Counted vmcnt (wave0 10, others 8) + raw s_barrier per K-step.
// LDS: A 3x2KB + W 8x2x8KB = 134KB -> 1 block/CU, 8 waves/CU.
// ---------------------------------------------------------------------------
__global__ __launch_bounds__(512) void wo_lnffn(
    const __hip_bfloat16* __restrict__ A,      // mix_bf [4096][512]
    const __hip_bfloat16* __restrict__ W,      // Wo_bf  [512][512]
    const float* __restrict__ bo,
    const float* __restrict__ x,
    const float* __restrict__ lw, const float* __restrict__ lb,
    float* __restrict__ x1, const float* __restrict__ phi,
    const float* __restrict__ W1,              // fp32 [2048][8]
    const float* __restrict__ b1,
    __hip_bfloat16* __restrict__ hq, __hip_bfloat16* __restrict__ hc,
    const float* __restrict__ gateF)
{
  __shared__ __align__(16) __hip_bfloat16 sh[68608];   // 134 KB
  const int tid = threadIdx.x;
  const int wid = tid >> 6;
  const int lane = tid & 63;
  const long m0 = (long)blockIdx.x * 16;
  const long n0w = (long)wid * 64;

  const int srow = lane >> 3;               // 0..7
  const int gchunk = (lane & 7) ^ srow;     // pre-swizzled global source
  const int frow = lane & 15;
  const int fk = lane >> 4;                 // 0..3

  __hip_bfloat16* shA = sh;                       // 3 slots x 1024 bf16
  __hip_bfloat16* shW = sh + 3072 + wid * 8192;   // 2 slots x 4096 bf16

  auto stageA = [&](int kt, int slot) {           // wave 0 only; 2 instrs
    __hip_bfloat16* buf = shA + slot * 1024;
#pragma unroll
    for (int i = 0; i < 2; ++i) {
      const int row = i * 8 + srow;               // 0..15
      GLOBAL_LOAD_LDS16(A + (m0 + row) * 512 + kt + gchunk * 8, buf + i * 512);
    }
  };
  auto stageW = [&](int kt, int slot) {           // 8 instrs
    __hip_bfloat16* buf = shW + slot * 4096;
#pragma unroll
    for (int i = 0; i < 8; ++i) {
      const int row = i * 8 + srow;
      GLOBAL_LOAD_LDS16(W + (n0w + row) * 512 + kt + gchunk * 8, buf + i * 512);
    }
  };

  floatx4 acc[4];
#pragma unroll
  for (int j = 0; j < 4; ++j) acc[j] = (floatx4){0.f, 0.f, 0.f, 0.f};

  // Prologue: wave0 issue order A0,W0,A1,W1 so vmcnt(10) leaves {A1,W1}.
  if (wid == 0) stageA(0, 0);
  stageW(0, 0);
  if (wid == 0) stageA(64, 1);
  stageW(64, 1);

  for (int t = 0; t < 8; ++t) {
    const int wslot = t & 1;
    const int aslot = t % 3;
    if (t < 7) { if (wid == 0) WAIT_VMCNT10(); else WAIT_VMCNT8(); }
    else       { WAIT_VMCNT0(); }
    // wave0 passed its wait => A(t) landed; barrier publishes it to all.
    BARRIER();

    short8 af[2], bf[2][4];
#pragma unroll
    for (int ks = 0; ks < 2; ++ks) {
      af[ks] = *(const short8*)(shA + aslot * 1024 + frow * 64 +
                                (((ks * 4 + fk) ^ (frow & 7)) << 3));
#pragma unroll
      for (int j = 0; j < 4; ++j) {
        const int wr = j * 16 + frow;
        bf[ks][j] = *(const short8*)(shW + wslot * 4096 + wr * 64 +
                                     (((ks * 4 + fk) ^ (wr & 7)) << 3));
      }
    }
    WAIT_LGKM0();                       // frags in VGPR before slot reuse
    if (t < 6) {
      // A(t+2) -> slot (t+2)%3 == (t-1)%3: every wave retired its reads of
      // tile t-1 before reaching this iteration's barrier. W slot private.
      if (wid == 0) stageA((t + 2) << 6, (t + 2) % 3);
      stageW((t + 2) << 6, wslot);
    }
#pragma unroll
    for (int ks = 0; ks < 2; ++ks)
#pragma unroll
      for (int j = 0; j < 4; ++j)
        acc[j] = __builtin_amdgcn_mfma_f32_16x16x32_bf16(
            af[ks], bf[ks][j], acc[j], 0, 0, 0);
  }

  // All waves completed frag reads (own lgkm0 at t=7) before this barrier;
  // attnL (33KB) overlaps shA + shW of waves 0/1 -> barrier REQUIRED.
  BARRIER();

  float* attnL = (float*)sh;            // [16][516] fp32 (pad 516: 2-way max)
  float* qmL = attnL + 16 * 516;        // [16][8]
  float* xsL = qmL + 128;               // [16][8]
  {
    const int col_l = lane & 15;
    const int row_l = (lane >> 4) << 2;
#pragma unroll
    for (int j = 0; j < 4; ++j) {
      const int c = (int)n0w + j * 16 + col_l;
      const float bv = bo[c];
#pragma unroll
      for (int r = 0; r < 4; ++r)
        attnL[(row_l + r) * 516 + c] = acc[j][r] + bv;
    }
  }
  WAIT_LGKM0();
  BARRIER();

  // LN1 over 512 cols: 32 threads per row, shfl-xor reduce within width 32.
  const int rr = tid >> 5;              // 0..15
  const int cl = tid & 31;
  const long rowg = m0 + rr;
  float sv[16];
  float sum = 0.f, ssq = 0.f;
#pragma unroll
  for (int i = 0; i < 16; ++i) {
    const int c = cl + i * 32;
    const float v = x[rowg * 512 + c] + attnL[rr * 516 + c];
    sv[i] = v; sum += v; ssq += v * v;
  }
#pragma unroll
  for (int off = 16; off > 0; off >>= 1) {
    sum += __shfl_xor(sum, off, 32);
    ssq += __shfl_xor(ssq, off, 32);
  }
  const float mean = sum * (1.0f / 512.0f);
  const float var = ssq * (1.0f / 512.0f) - mean * mean;
  const float rstd = rsqrtf(fmaxf(var, 0.0f) + 1e-5f);
#pragma unroll
  for (int i = 0; i < 16; ++i) {
    const int c = cl + i * 32;
    const float o = (sv[i] - mean) * rstd * lw[c] + lb[c];
    x1[rowg * 512 + c] = o;
    if (i == 0 && cl < 8) {
      qmL[rr * 8 + cl] = __cosf(o) * __cosf(phi[cl]);
      xsL[rr * 8 + cl] = o;
    }
  }
  WAIT_LGKM0();
  BARRIER();

  // FFN-h: thread owns outputs n = tid*4 .. tid*4+3 for all 16 rows.
  const int n4 = tid << 2;
  float w1r[4][8];
#pragma unroll
  for (int jr = 0; jr < 4; ++jr) {
    float4 wa = *(const float4*)(W1 + (long)(n4 + jr) * 8);
    float4 wb = *(const float4*)(W1 + (long)(n4 + jr) * 8 + 4);
    w1r[jr][0] = wa.x; w1r[jr][1] = wa.y; w1r[jr][2] = wa.z; w1r[jr][3] = wa.w;
    w1r[jr][4] = wb.x; w1r[jr][5] = wb.y; w1r[jr][6] = wb.z; w1r[jr][7] = wb.w;
  }
  float4 bb = *(const float4*)(b1 + n4);
  const float b1a[4] = {bb.x, bb.y, bb.z, bb.w};
  const float gv = *gateF;
#pragma unroll 2
  for (int r = 0; r < 16; ++r) {
    float qm8[8];
#pragma unroll
    for (int k = 0; k < 8; ++k) qm8[k] = qmL[r * 8 + k];   // LDS broadcast
    union { unsigned short u16[4]; ushort4 v; } pk;
#pragma unroll
    for (int jr = 0; jr < 4; ++jr) {
      float a = b1a[jr];
#pragma unroll
      for (int k = 0; k < 8; ++k) a += qm8[k] * w1r[jr][k];
      pk.u16[jr] = f2bf_bits(fmaxf(a, 0.0f));
    }
    *(ushort4*)(hq + (m0 + r) * 2048 + n4) = pk.v;
    if (gv != 1.0f) {
      float xs8[8];
#pragma unroll
      for (int k = 0; k < 8; ++k) xs8[k] = xsL[r * 8 + k];
#pragma unroll
      for (int jr = 0; jr < 4; ++jr) {
        float a = b1a[jr];
#pragma unroll
        for (int k = 0; k < 8; ++k) a += xs8[k] * w1r[jr][k];
        pk.u16[jr] = f2bf_bits(fmaxf(a, 0.0f));
      }
      *(ushort4*)(hc + (m0 + r) * 2048 + n4) = pk.v;
    }
  }
}

// ---------------------------------------------------------------------------
// FFN-out (R14 form): grid (64, 8, 2) x 128 threads (2-wave K-split).
// z=0: Fb = hq@W2^T+b2 (bf16). z=1 (cond gateF!=1): Fc = hc@W2^T+b2.
// ---------------------------------------------------------------------------
__global__ __launch_bounds__(128) void gemm_ffnout(
    const __hip_bfloat16* __restrict__ hq,
    const __hip_bfloat16* __restrict__ hc,
    const __hip_bfloat16* __restrict__ W2, const float* __restrict__ b2,
    __hip_bfloat16* __restrict__ Fb, __hip_bfloat16* __restrict__ Fc,
    const float* __restrict__ gateF)
{
  const int z = blockIdx.z;
  if (z == 1 && *gateF == 1.0f) return;
  const __hip_bfloat16* A = z ? hc : hq;
  __hip_bfloat16* C = z ? Fc : Fb;
  __shared__ __align__(16) __hip_bfloat16 sh[32768];   // 64 KB: 2 x ring-2
  const int tid = threadIdx.x;
  const int wid = tid >> 6;
  const int lane = tid & 63;
  const long m0 = (long)blockIdx.x * 64;
  const long n0 = (long)blockIdx.y * 64;
  floatx4 acc[4][4];
#pragma unroll
  for (int i = 0; i < 4; ++i)
#pragma unroll
    for (int j = 0; j < 4; ++j) acc[i][j] = (floatx4){0.f, 0.f, 0.f, 0.f};
  gemm_core_ks(A, W2, 2048, wid * 1024, 16, m0, n0, lane, sh + wid * 16384, acc);
  if (!ks_reduce(acc, sh, wid, lane)) return;   // wave0 continues
  store_bf16(acc, C, b2, m0, n0, lane);
}

// ---------------------------------------------------------------------------
// input prep: fp32->bf16 for x, Wq, Wo, W2; conditional Wk/Wv.
// (W1 stays fp32 — consumed directly by wo_lnffn.)
// ---------------------------------------------------------------------------
__device__ __forceinline__ void cvt_one(const float* s, __hip_bfloat16* d, int n,
                                        long tid, long stride) {
  const int n4 = n >> 2;
  for (long i = tid; i < n4; i += stride) {
    float4 v = ((const float4*)s)[i];
    ushort4 u;
    u.x = f2bf_bits(v.x); u.y = f2bf_bits(v.y);
    u.z = f2bf_bits(v.z); u.w = f2bf_bits(v.w);
    ((ushort4*)d)[i] = u;
  }
}

__global__ __launch_bounds__(256) void prep_inputs(
    const float* x, __hip_bfloat16* x_bf,
    const float* Wq, __hip_bfloat16* Wq_bf,
    const float* Wo, __hip_bfloat16* Wo_bf,
    const float* W2, __hip_bfloat16* W2_bf,
    const float* Wk, __hip_bfloat16* Wk_bf,
    const float* Wv, __hip_bfloat16* Wv_bf,
    const float* gateA)
{
  const long stride = (long)gridDim.x * blockDim.x;
  const long tid = (long)blockIdx.x * blockDim.x + threadIdx.x;
  cvt_one(x, x_bf, 4096 * 512, tid, stride);
  cvt_one(Wq, Wq_bf, 512 * 512, tid, stride);
  cvt_one(Wo, Wo_bf, 512 * 512, tid, stride);
  cvt_one(W2, W2_bf, 512 * 2048, tid, stride);
  if (*gateA != 1.0f) {
    cvt_one(Wk, Wk_bf, 512 * 512, tid, stride);
    cvt_one(Wv, Wv_bf, 512 * 512, tid, stride);
  }
}

// ---------------------------------------------------------------------------
// [cond gateA!=1] classical softmax attention + blend into mix (bf16).
// ---------------------------------------------------------------------------
__global__ __launch_bounds__(256) void attn_blend(
    const float* __restrict__ Qb, const float* __restrict__ Kb,
    const float* __restrict__ Vb, __hip_bfloat16* __restrict__ mix,
    const float* __restrict__ gateA)
{
  const float g = *gateA;
  if (g == 1.0f) return;
  const int idx = blockIdx.x * blockDim.x + threadIdx.x;
  if (idx >= 4 * 64 * 1024) return;
  const int s = idx & 1023;
  const int h = (idx >> 10) & 63;
  const int b = idx >> 16;
  const long qoff = ((long)(b * 1024 + s)) * 512 + h * 8;
  float q[8];
#pragma unroll
  for (int i = 0; i < 8; ++i) q[i] = Qb[qoff + i] * 0.35355339059327373f;
  float m = -INFINITY, l = 0.0f, acc[8];
#pragma unroll
  for (int i = 0; i < 8; ++i) acc[i] = 0.0f;
  for (int t = 0; t < 1024; ++t) {
    const long koff = ((long)(b * 1024 + t)) * 512 + h * 8;
    const float* kr = Kb + koff;
    const float* vr = Vb + koff;
    float sc = 0.0f;
#pragma unroll
    for (int i = 0; i < 8; ++i) sc += q[i] * kr[i];
    float nm = fmaxf(m, sc);
    float corr = __expf(m - nm);
    float p = __expf(sc - nm);
    l = l * corr + p;
#pragma unroll
    for (int i = 0; i < 8; ++i) acc[i] = acc[i] * corr + p * vr[i];
    m = nm;
  }
  const float inv = 1.0f / l;
  union { unsigned short u16[8]; uint4 v; } pk;
  pk.v = *(const uint4*)(mix + qoff);
#pragma unroll
  for (int i = 0; i < 8; ++i) {
    float quant = bfbits2f(pk.u16[i]);
    pk.u16[i] = f2bf_bits(g * quant + (1.0f - g) * acc[i] * inv);
  }
  *(uint4*)(mix + qoff) = pk.v;
}

// ---------------------------------------------------------------------------
// Final LN: out = LN(x1 + mix(Fb, Fc; gateF)), Fb/Fc bf16 (R12).
// Wave-per-row, 4 rows/block, no barriers. grid 1024.
// ---------------------------------------------------------------------------
__global__ __launch_bounds__(256) void add_ln3(
    const float* __restrict__ x1, const __hip_bfloat16* __restrict__ Fb,
    const __hip_bfloat16* __restrict__ Fc, const float* __restrict__ gateF,
    const float* __restrict__ lw, const float* __restrict__ lb,
    float* __restrict__ out)
{
  const int tid = threadIdx.x;
  const int wv = tid >> 6, lane = tid & 63;
  const int row = blockIdx.x * 4 + wv;
  const long base = (long)row * 512;
  const int c0 = lane * 8;
  float4 a0 = *(const float4*)(x1 + base + c0);
  float4 a1 = *(const float4*)(x1 + base + c0 + 4);
  union { unsigned short u16[8]; uint4 v; } fb;
  fb.v = *(const uint4*)(Fb + base + c0);
  const float xa[8] = {a0.x, a0.y, a0.z, a0.w, a1.x, a1.y, a1.z, a1.w};
  float s[8];
  const float gv = *gateF;
  if (gv != 1.0f) {
    union { unsigned short u16[8]; uint4 v; } fc;
    fc.v = *(const uint4*)(Fc + base + c0);
    const float om = 1.0f - gv;
#pragma unroll
    for (int i = 0; i < 8; ++i)
      s[i] = xa[i] + gv * bfbits2f(fb.u16[i]) + om * bfbits2f(fc.u16[i]);
  } else {
#pragma unroll
    for (int i = 0; i < 8; ++i) s[i] = xa[i] + bfbits2f(fb.u16[i]);
  }
  float sum = 0.f, ssq = 0.f;
#pragma unroll
  for (int i = 0; i < 8; ++i) { sum += s[i]; ssq += s[i] * s[i]; }
#pragma unroll
  for (int off = 32; off > 0; off >>= 1) {
    sum += __shfl_xor(sum, off);
    ssq += __shfl_xor(ssq, off);
  }
  const float mean = sum * (1.0f / 512.0f);
  const float var = ssq * (1.0f / 512.0f) - mean * mean;
  const float rstd = rsqrtf(fmaxf(var, 0.0f) + 1e-5f);
  float4 w0 = *(const float4*)(lw + c0);
  float4 w1 = *(const float4*)(lw + c0 + 4);
  float4 g0 = *(const float4*)(lb + c0);
  float4 g1 = *(const float4*)(lb + c0 + 4);
  const float wf[8] = {w0.x, w0.y, w0.z, w0.w, w1.x, w1.y, w1.z, w1.w};
  const float gf8[8] = {g0.x, g0.y, g0.z, g0.w, g1.x, g1.y, g1.z, g1.w};
  float o[8];
#pragma unroll
  for (int i = 0; i < 8; ++i) o[i] = (s[i] - mean) * rstd * wf[i] + gf8[i];
  *(float4*)(out + base + c0) = (float4){o[0], o[1], o[2], o[3]};
  *(float4*)(out + base + c0 + 4) = (float4){o[4], o[5], o[6], o[7]};
}

// ---------------------------------------------------------------------------
extern "C" void kernel_launch(void* const* d_in, const int* in_sizes, int n_in,
                              void* d_out, int out_size, void* d_ws, size_t ws_size,
                              hipStream_t stream) {
  const float* x     = (const float*)d_in[0];
  const float* Wq    = (const float*)d_in[1];
  const float* bq    = (const float*)d_in[2];
  const float* Wk    = (const float*)d_in[3];
  const float* bk    = (const float*)d_in[4];
  const float* Wv    = (const float*)d_in[5];
  const float* bv    = (const float*)d_in[6];
  const float* theta = (const float*)d_in[7];
  const float* gateA = (const float*)d_in[8];
  const float* Wo    = (const float*)d_in[9];
  const float* bo    = (const float*)d_in[10];
  const float* ln1w  = (const float*)d_in[11];
  const float* ln1b  = (const float*)d_in[12];
  const float* W1    = (const float*)d_in[13];
  const float* b1    = (const float*)d_in[14];
  const float* W2    = (const float*)d_in[15];
  const float* b2    = (const float*)d_in[16];
  const float* phi   = (const float*)d_in[17];
  const float* gateF = (const float*)d_in[18];
  const float* ln2w  = (const float*)d_in[19];
  const float* ln2b  = (const float*)d_in[20];
  float* out = (float*)d_out;

  const size_t MB = 1024 * 1024;
  char* wsb = (char*)d_ws;
  __hip_bfloat16* x_bf    = (__hip_bfloat16*)(wsb + 0 * MB);            // 4 MB
  __hip_bfloat16* Wq_bf   = (__hip_bfloat16*)(wsb + 4 * MB);            // 0.5 MB
  __hip_bfloat16* Wo_bf   = (__hip_bfloat16*)(wsb + 4 * MB + 512 * 1024);
  __hip_bfloat16* W2_bf   = (__hip_bfloat16*)(wsb + 5 * MB);            // 2 MB
  __hip_bfloat16* mix_bf  = (__hip_bfloat16*)(wsb + 8 * MB);            // 4 MB
  float*          x1      = (float*)(wsb + 16 * MB);                    // 8 MB
  __hip_bfloat16* hq_bf   = (__hip_bfloat16*)(wsb + 24 * MB);           // 16 MB
  __hip_bfloat16* Fb_bf   = (__hip_bfloat16*)(wsb + 40 * MB);           // 4 MB
  // conditional (gate != 1) buffers
  float*          Qb      = (float*)(wsb + 52 * MB);                    // 8 MB
  __hip_bfloat16* Wk_bf   = (__hip_bfloat16*)(wsb + 60 * MB);
  __hip_bfloat16* Wv_bf   = (__hip_bfloat16*)(wsb + 60 * MB + 512 * 1024);
  float*          Kb2     = (float*)(wsb + 61 * MB);                    // 8 MB
  float*          Vb2     = (float*)(wsb + 69 * MB);                    // 8 MB
  __hip_bfloat16* hc_bf   = (__hip_bfloat16*)(wsb + 77 * MB);           // 16 MB
  __hip_bfloat16* Fc_bf   = (__hip_bfloat16*)(wsb + 93 * MB);           // 4 MB

  // 1. input prep (all conversions; W1 stays fp32)
  prep_inputs<<<1024, 256, 0, stream>>>(
      x, x_bf, Wq, Wq_bf, Wo, Wo_bf, W2, W2_bf, Wk, Wk_bf, Wv, Wv_bf, gateA);
  // 2. QKV 32x32 single-wave (R18): z=0 Q+quantum -> mix_bf (+Qb cond);
  //    z=1/2 K/V (cond). n-inner grid for A-slice L2 reuse.
  gemm_qkv<<<dim3(16, 128, 3), 64, 0, stream>>>(
      x_bf, Wq_bf, Wk_bf, Wv_bf, bq, bk, bv,
      mix_bf, Qb, Kb2, Vb2, theta, gateA);
  // 3. [cond] classical attention + blend into mix_bf
  attn_blend<<<1024, 256, 0, stream>>>(Qb, Kb2, Vb2, mix_bf, gateA);
  // 4. R13 fused: attn = mix@Wo^T+bo ; x1 = LN1(x+attn) ; hq (+hc cond)
  wo_lnffn<<<256, 512, 0, stream>>>(
      mix_bf, Wo_bf, bo, x, ln1w, ln1b, x1, phi, W1, b1, hq_bf, hc_bf, gateF);
  // 5. Fb = hq @ W2^T + b2 (z=0); Fc = hc @ W2^T + b2 (z=1, cond), bf16
  gemm_ffnout<<<dim3(64, 8, 2), 128, 0, stream>>>(
      hq_bf, hc_bf, W2_bf, b2, Fb_bf, Fc_bf, gateF);
  // 6. out = LN(x1 + gF*Fb + (1-gF)*Fc)
  add_ln3<<<1024, 256, 0, stream>>>(x1, Fb_bf, Fc_bf, gateF, ln2w, ln2b, out);
}

// Round 7
// 142.797 us; speedup vs baseline: 1.1759x; 1.0416x over previous
//
#include <hip/hip_runtime.h>
#include <hip/hip_bf16.h>

// Shapes fixed by the problem:
// B=4, S=1024, D=512, H=64, DK=8, FF=2048, NQ=8. Mtok = B*S = 4096.
// R10: multi-dispatch beats persistent mega-kernel.
// R12: bf16 intermediates. R13: wo_lnffn fusion.
// R14: K-split-2 LDS-staged qkv/ffnout = BEST 146.3.
// R15 (+21), R16 (+12), R17 (+3), R18 (+2): four structurally different
// GEMM cores all land in the 146-168 band -> GEMM time is NOT the lever;
// budget closes as: ~86us workspace-poison fills (harness-fixed, the only
// dispatches visible in top-5) + boundaries + ~40us serial kernel chain.
// R19: minimal serial chain: qkv reverted to R14 exact; attn_blend dispatch
// DELETED (folded into wo_lnffn prologue; no-op when gateA==1). 5 dispatches.

typedef short short8 __attribute__((ext_vector_type(8)));
typedef float floatx4 __attribute__((ext_vector_type(4)));

__device__ __forceinline__ unsigned short f2bf_bits(float f) {
  __hip_bfloat16 h = __float2bfloat16(f);
  return *reinterpret_cast<unsigned short*>(&h);
}
__device__ __forceinline__ float bfbits2f(unsigned short u) {
  union { unsigned int u; float f; } c;
  c.u = (unsigned int)u << 16;
  return c.f;
}

#define GLOBAL_LOAD_LDS16(g, l)                                               \
  __builtin_amdgcn_global_load_lds(                                           \
      (const __attribute__((address_space(1))) void*)(g),                     \
      (__attribute__((address_space(3))) void*)(l), 16, 0, 0)

// Compiler does NOT model global_load_lds's LDS write as aliasing later LDS
// reads. Explicit waits; memory clobber pins ordering.
#define WAIT_VMCNT0()   asm volatile("s_waitcnt vmcnt(0)" ::: "memory")
#define WAIT_VMCNT8()   asm volatile("s_waitcnt vmcnt(8)" ::: "memory")
#define WAIT_VMCNT10()  asm volatile("s_waitcnt vmcnt(10)" ::: "memory")
#define WAIT_VMCNT16()  asm volatile("s_waitcnt vmcnt(16)" ::: "memory")
#define WAIT_LGKM0()    asm volatile("s_waitcnt lgkmcnt(0)" ::: "memory")
#define BARRIER()       __builtin_amdgcn_s_barrier()
#define CFENCE()        asm volatile("" ::: "memory")

// ---------------------------------------------------------------------------
// Per-wave GEMM core over a K-range, ring-2 staging (32 KB / wave):
// acc(64x64) += A[:, kr] @ W[:, kr]^T. 4x4 of 16x16x32 MFMA, BK=64.
// XOR chunk swizzle: phys 16B chunk p of row r holds logical chunk
// p ^ (r&7) -> conflict-free ds_read_b128. (R14 core, unchanged.)
// ---------------------------------------------------------------------------
__device__ __forceinline__ void gemm_core_ks(
    const __hip_bfloat16* __restrict__ A,
    const __hip_bfloat16* __restrict__ W,
    int K, int kbeg, int ntiles, long m0, long n0, int lane,
    __hip_bfloat16* sh, floatx4 acc[4][4])
{
  const int srow = lane >> 3;
  const int gchunk = (lane & 7) ^ srow;
  const int frow = lane & 15;
  const int fk = lane >> 4;

  auto stage = [&](int kt, __hip_bfloat16* buf) {
#pragma unroll
    for (int ib = 0; ib < 8; ++ib) {
      const int row = ib * 8 + srow;
      GLOBAL_LOAD_LDS16(A + (m0 + row) * K + kt + gchunk * 8, buf + ib * 512);
      GLOBAL_LOAD_LDS16(W + (n0 + row) * K + kt + gchunk * 8, buf + 4096 + ib * 512);
    }
  };

  WAIT_LGKM0();                         // prior LDS reads retired
  stage(kbeg, sh);
  if (ntiles > 1) stage(kbeg + 64, sh + 8192);

  for (int t = 0; t < ntiles; ++t) {
    __hip_bfloat16* buf = sh + (t & 1) * 8192;
    if (t < ntiles - 1) { WAIT_VMCNT16(); }   // current tile landed
    else               { WAIT_VMCNT0(); }

    short8 af[2][4], bf[2][4];
#pragma unroll
    for (int ks = 0; ks < 2; ++ks)
#pragma unroll
      for (int i = 0; i < 4; ++i) {
        const int ar = i * 16 + frow;
        af[ks][i] = *(const short8*)(buf + ar * 64 + (((ks * 4 + fk) ^ (ar & 7)) << 3));
        bf[ks][i] = *(const short8*)(buf + 4096 + ar * 64 + (((ks * 4 + fk) ^ (ar & 7)) << 3));
      }
    WAIT_LGKM0();                       // frags in VGPR before buf reuse
    if (t + 2 < ntiles) stage(kbeg + ((t + 2) << 6), buf);
#pragma unroll
    for (int ks = 0; ks < 2; ++ks)
#pragma unroll
      for (int i = 0; i < 4; ++i)
#pragma unroll
        for (int j = 0; j < 4; ++j)
          acc[i][j] = __builtin_amdgcn_mfma_f32_16x16x32_bf16(
              af[ks][i], bf[ks][j], acc[i][j], 0, 0, 0);
  }
}

// K-split reduce: wave1 dumps acc into its own ring slot 0 (16 KB fp32),
// wave0 adds. Returns true for the wave that continues (wave0).
__device__ __forceinline__ bool ks_reduce(
    floatx4 acc[4][4], __hip_bfloat16* sh, int wid, int lane)
{
  float* red = (float*)(sh + 16384);    // wave1 ring, slot 0
  if (wid == 1) {
#pragma unroll
    for (int i = 0; i < 4; ++i)
#pragma unroll
      for (int j = 0; j < 4; ++j)
        *(floatx4*)(red + ((i * 4 + j) * 64 + lane) * 4) = acc[i][j];
    WAIT_LGKM0();
  }
  CFENCE(); BARRIER(); CFENCE();
  if (wid == 1) return false;
#pragma unroll
  for (int i = 0; i < 4; ++i)
#pragma unroll
    for (int j = 0; j < 4; ++j)
      acc[i][j] += *(const floatx4*)(red + ((i * 4 + j) * 64 + lane) * 4);
  return true;
}

// fp32 store epilogue, N=512. D layout: row=(lane>>4)*4+reg, col=lane&15.
__device__ __forceinline__ void store_f32(
    floatx4 acc[4][4], float* __restrict__ C, const float* __restrict__ bias,
    long m0, long n0, int lane)
{
  const int col_l = lane & 15;
  const int row_l = (lane >> 4) << 2;
#pragma unroll
  for (int j = 0; j < 4; ++j) {
    const long col = n0 + j * 16 + col_l;
    const float bv = bias[col];
#pragma unroll
    for (int i = 0; i < 4; ++i)
#pragma unroll
      for (int r = 0; r < 4; ++r)
        C[(m0 + i * 16 + row_l + r) * 512 + col] = acc[i][j][r] + bv;
  }
}

// bf16 store epilogue (64x64).
__device__ __forceinline__ void store_bf16(
    floatx4 acc[4][4], __hip_bfloat16* __restrict__ C,
    const float* __restrict__ bias, long m0, long n0, int lane)
{
  const int col_l = lane & 15;
  const int row_l = (lane >> 4) << 2;
#pragma unroll
  for (int j = 0; j < 4; ++j) {
    const long col = n0 + j * 16 + col_l;
    const float bv = bias[col];
#pragma unroll
    for (int i = 0; i < 4; ++i)
#pragma unroll
      for (int r = 0; r < 4; ++r)
        C[(m0 + i * 16 + row_l + r) * 512 + col] =
            __float2bfloat16(acc[i][j][r] + bv);
  }
}

// ---------------------------------------------------------------------------
// QKV launch (R14 exact): grid (64, 8, 3) x 128 threads (2-wave K-split).
// z=0: Q = x@Wq^T+bq with fused quantum epilogue -> mix_bf (bf16); if
// *gateA != 1 also writes Qb fp32. z=1/2: conditional K/V projections.
// ---------------------------------------------------------------------------
__global__ __launch_bounds__(128) void gemm_qkv(
    const __hip_bfloat16* __restrict__ x_bf,
    const __hip_bfloat16* __restrict__ Wq,
    const __hip_bfloat16* __restrict__ Wk,
    const __hip_bfloat16* __restrict__ Wv,
    const float* __restrict__ bq, const float* __restrict__ bk,
    const float* __restrict__ bvv,
    __hip_bfloat16* __restrict__ mix,
    float* __restrict__ Qb, float* __restrict__ Kb, float* __restrict__ Vb,
    const float* __restrict__ theta, const float* __restrict__ gateA)
{
  const int z = blockIdx.z;
  const float g = *gateA;
  if (z > 0 && g == 1.0f) return;
  const __hip_bfloat16* W = (z == 0) ? Wq : (z == 1) ? Wk : Wv;
  const float* bias = (z == 0) ? bq : (z == 1) ? bk : bvv;
  float* Cf = (z == 0) ? Qb : (z == 1) ? Kb : Vb;

  __shared__ __align__(16) __hip_bfloat16 sh[32768];   // 64 KB: 2 x ring-2
  const int tid = threadIdx.x;
  const int wid = tid >> 6;
  const int lane = tid & 63;
  const long m0 = (long)blockIdx.x * 64;
  const long n0 = (long)blockIdx.y * 64;
  floatx4 acc[4][4];
#pragma unroll
  for (int i = 0; i < 4; ++i)
#pragma unroll
    for (int j = 0; j < 4; ++j) acc[i][j] = (floatx4){0.f, 0.f, 0.f, 0.f};

  gemm_core_ks(x_bf, W, 512, wid * 256, 4, m0, n0, lane, sh + wid * 16384, acc);
  if (!ks_reduce(acc, sh, wid, lane)) return;   // wave0 continues

  const int col_l = lane & 15;
  const int row_l = (lane >> 4) << 2;

  if (z > 0 || g != 1.0f) store_f32(acc, Cf, bias, m0, n0, lane);
  if (z == 0) {
    // quantum epilogue: LDS-transpose acc(+bias), then per 8-wide head
    // group o[0]=c1..c7, o[j>=1]=c0..cj with c=cos(q+theta). Single wave:
    // DS pipe in-order; lgkm fences pin ordering/completion. shf uses
    // wave0's ring [0,16KB) — no overlap with red buffer at [32KB,48KB).
    float* shf = (float*)sh;   // 64x64 fp32 = 16 KB
    WAIT_LGKM0();
#pragma unroll
    for (int j = 0; j < 4; ++j) {
      const long col = n0 + j * 16 + col_l;
      const float bv = bias[col];
#pragma unroll
      for (int i = 0; i < 4; ++i)
#pragma unroll
        for (int r = 0; r < 4; ++r)
          shf[(i * 16 + row_l + r) * 64 + j * 16 + col_l] = acc[i][j][r] + bv;
    }
    WAIT_LGKM0();
    float th[8];
#pragma unroll
    for (int i = 0; i < 8; ++i) th[i] = theta[i];
#pragma unroll
    for (int t = 0; t < 8; ++t) {
      const int gidx = t * 64 + lane;
      const int row = gidx >> 3;
      const int hh = gidx & 7;
      const float* src = shf + row * 64 + hh * 8;
      float c[8];
#pragma unroll
      for (int i = 0; i < 8; ++i) c[i] = __cosf(src[i] + th[i]);
      float o[8];
      float p = c[1];
#pragma unroll
      for (int i = 2; i < 8; ++i) p *= c[i];
      o[0] = p;
      float cp = c[0];
#pragma unroll
      for (int i = 1; i < 8; ++i) { cp *= c[i]; o[i] = cp; }
      union { unsigned short u16[8]; uint4 v; } pk;
#pragma unroll
      for (int i = 0; i < 8; ++i) pk.u16[i] = f2bf_bits(o[i]);
      *(uint4*)(mix + (m0 + row) * 512 + n0 + hh * 8) = pk.v;
    }
  }
}

// ---------------------------------------------------------------------------
// R13 fused kernel + R19 fused blend: [cond g!=1: blend classical attn into
// this block's 16 mix rows] ; attn = mix @ Wo^T + bo ; x1 = LN1(x + attn) ;
// qm/xs -> hq (and cond hc). One block owns 16 rows x all 512 cols.
// grid 256, blockDim 512 (8 waves). Wave w computes cols [64w, 64w+64).
// A-tile staged by wave0, SHARED; W-tile private per wave. A ring-3, W
// ring-2. Counted vmcnt (wave0 10, others 8) + raw s_barrier per K-step.
// LDS: A 3x2KB + W 8x2x8KB = 134KB -> 1 block/CU, 8 waves/CU.
// Blend correctness: mix rows m0..m0+16 are read ONLY by this block (A-tile
// rows are block-exclusive); Qb/Kb/Vb complete from the prior dispatch;
// stores drained (vmcnt0) + barrier before staging re-reads mix.
// ---------------------------------------------------------------------------
__global__ __launch_bounds__(512) void wo_lnffn(
    const __hip_bfloat16* __restrict__ A,      // mix_bf [4096][512]
    const __hip_bfloat16* __restrict__ W,      // Wo_bf  [512][512]
    const float* __restrict__ bo,
    const float* __restrict__ x,
    const float* __restrict__ lw, const float* __restrict__ lb,
    float* __restrict__ x1, const float* __restrict__ phi,
    const float* __restrict__ W1,              // fp32 [2048][8]
    const float* __restrict__ b1,
    __hip_bfloat16* __restrict__ hq, __hip_bfloat16* __restrict__ hc,
    const float* __restrict__ gateF,
    __hip_bfloat16* __restrict__ mix_rw,       // non-const alias of A
    const float* __restrict__ Qb, const float* __restrict__ Kb,
    const float* __restrict__ Vb, const float* __restrict__ gateA)
{
  __shared__ __align__(16) __hip_bfloat16 sh[68608];   // 134 KB
  const int tid = threadIdx.x;
  const int wid = tid >> 6;
  const int lane = tid & 63;
  const long m0 = (long)blockIdx.x * 16;
  const long n0w = (long)wid * 64;

  // [R19] fused attn_blend (g != 1 only; uniform branch, else zero cost).
  const float g = *gateA;
  if (g != 1.0f) {
#pragma unroll 1
    for (int p = tid * 2; p < tid * 2 + 2; ++p) {
      const int r = p >> 6;               // 0..15
      const int h = p & 63;
      const long row = m0 + r;
      const int b = (int)(row >> 10);
      const long qoff = row * 512 + h * 8;
      float q[8];
#pragma unroll
      for (int i = 0; i < 8; ++i) q[i] = Qb[qoff + i] * 0.35355339059327373f;
      float m = -INFINITY, l = 0.0f, acc8[8];
#pragma unroll
      for (int i = 0; i < 8; ++i) acc8[i] = 0.0f;
      for (int t = 0; t < 1024; ++t) {
        const long koff = ((long)(b * 1024 + t)) * 512 + h * 8;
        const float* kr = Kb + koff;
        const float* vr = Vb + koff;
        float sc = 0.0f;
#pragma unroll
        for (int i = 0; i < 8; ++i) sc += q[i] * kr[i];
        float nm = fmaxf(m, sc);
        float corr = __expf(m - nm);
        float pp = __expf(sc - nm);
        l = l * corr + pp;
#pragma unroll
        for (int i = 0; i < 8; ++i) acc8[i] = acc8[i] * corr + pp * vr[i];
        m = nm;
      }
      const float inv = 1.0f / l;
      union { unsigned short u16[8]; uint4 v; } pk;
      pk.v = *(const uint4*)(mix_rw + qoff);
#pragma unroll
      for (int i = 0; i < 8; ++i) {
        float quant = bfbits2f(pk.u16[i]);
        pk.u16[i] = f2bf_bits(g * quant + (1.0f - g) * acc8[i] * inv);
      }
      *(uint4*)(mix_rw + qoff) = pk.v;
    }
    WAIT_VMCNT0();                        // blended rows in L2
    CFENCE(); BARRIER(); CFENCE();        // visible to wave0's stageA
  }

  const int srow = lane >> 3;               // 0..7
  const int gchunk = (lane & 7) ^ srow;     // pre-swizzled global source
  const int frow = lane & 15;
  const int fk = lane >> 4;                 // 0..3

  __hip_bfloat16* shA = sh;                       // 3 slots x 1024 bf16
  __hip_bfloat16* shW = sh + 3072 + wid * 8192;   // 2 slots x 4096 bf16

  auto stageA = [&](int kt, int slot) {           // wave 0 only; 2 instrs
    __hip_bfloat16* buf = shA + slot * 1024;
#pragma unroll
    for (int i = 0; i < 2; ++i) {
      const int row = i * 8 + srow;               // 0..15
      GLOBAL_LOAD_LDS16(A + (m0 + row) * 512 + kt + gchunk * 8, buf + i * 512);
    }
  };
  auto stageW = [&](int kt, int slot) {           // 8 instrs
    __hip_bfloat16* buf = shW + slot * 4096;
#pragma unroll
    for (int i = 0; i < 8; ++i) {
      const int row = i * 8 + srow;
      GLOBAL_LOAD_LDS16(W + (n0w + row) * 512 + kt + gchunk * 8, buf + i * 512);
    }
  };

  floatx4 acc[4];
#pragma unroll
  for (int j = 0; j < 4; ++j) acc[j] = (floatx4){0.f, 0.f, 0.f, 0.f};

  // Prologue: wave0 issue order A0,W0,A1,W1 so vmcnt(10) leaves {A1,W1}.
  if (wid == 0) stageA(0, 0);
  stageW(0, 0);
  if (wid == 0) stageA(64, 1);
  stageW(64, 1);

  for (int t = 0; t < 8; ++t) {
    const int wslot = t & 1;
    const int aslot = t % 3;
    if (t < 7) { if (wid == 0) WAIT_VMCNT10(); else WAIT_VMCNT8(); }
    else       { WAIT_VMCNT0(); }
    // wave0 passed its wait => A(t) landed; barrier publishes it to all.
    BARRIER();

    short8 af[2], bf[2][4];
#pragma unroll
    for (int ks = 0; ks < 2; ++ks) {
      af[ks] = *(const short8*)(shA + aslot * 1024 + frow * 64 +
                                (((ks * 4 + fk) ^ (frow & 7)) << 3));
#pragma unroll
      for (int j = 0; j < 4; ++j) {
        const int wr = j * 16 + frow;
        bf[ks][j] = *(const short8*)(shW + wslot * 4096 + wr * 64 +
                                     (((ks * 4 + fk) ^ (wr & 7)) << 3));
      }
    }
    WAIT_LGKM0();                       // frags in VGPR before slot reuse
    if (t < 6) {
      // A(t+2) -> slot (t+2)%3 == (t-1)%3: every wave retired its reads of
      // tile t-1 before reaching this iteration's barrier. W slot private.
      if (wid == 0) stageA((t + 2) << 6, (t + 2) % 3);
      stageW((t + 2) << 6, wslot);
    }
#pragma unroll
    for (int ks = 0; ks < 2; ++ks)
#pragma unroll
      for (int j = 0; j < 4; ++j)
        acc[j] = __builtin_amdgcn_mfma_f32_16x16x32_bf16(
            af[ks], bf[ks][j], acc[j], 0, 0, 0);
  }

  // All waves completed frag reads (own lgkm0 at t=7) before this barrier;
  // attnL (33KB) overlaps shA + shW of waves 0/1 -> barrier REQUIRED.
  BARRIER();

  float* attnL = (float*)sh;            // [16][516] fp32 (pad 516: 2-way max)
  float* qmL = attnL + 16 * 516;        // [16][8]
  float* xsL = qmL + 128;               // [16][8]
  {
    const int col_l = lane & 15;
    const int row_l = (lane >> 4) << 2;
#pragma unroll
    for (int j = 0; j < 4; ++j) {
      const int c = (int)n0w + j * 16 + col_l;
      const float bv = bo[c];
#pragma unroll
      for (int r = 0; r < 4; ++r)
        attnL[(row_l + r) * 516 + c] = acc[j][r] + bv;
    }
  }
  WAIT_LGKM0();
  BARRIER();

  // LN1 over 512 cols: 32 threads per row, shfl-xor reduce within width 32.
  const int rr = tid >> 5;              // 0..15
  const int cl = tid & 31;
  const long rowg = m0 + rr;
  float sv[16];
  float sum = 0.f, ssq = 0.f;
#pragma unroll
  for (int i = 0; i < 16; ++i) {
    const int c = cl + i * 32;
    const float v = x[rowg * 512 + c] + attnL[rr * 516 + c];
    sv[i] = v; sum += v; ssq += v * v;
  }
#pragma unroll
  for (int off = 16; off > 0; off >>= 1) {
    sum += __shfl_xor(sum, off, 32);
    ssq += __shfl_xor(ssq, off, 32);
  }
  const float mean = sum * (1.0f / 512.0f);
  const float var = ssq * (1.0f / 512.0f) - mean * mean;
  const float rstd = rsqrtf(fmaxf(var, 0.0f) + 1e-5f);
#pragma unroll
  for (int i = 0; i < 16; ++i) {
    const int c = cl + i * 32;
    const float o = (sv[i] - mean) * rstd * lw[c] + lb[c];
    x1[rowg * 512 + c] = o;
    if (i == 0 && cl < 8) {
      qmL[rr * 8 + cl] = __cosf(o) * __cosf(phi[cl]);
      xsL[rr * 8 + cl] = o;
    }
  }
  WAIT_LGKM0();
  BARRIER();

  // FFN-h: thread owns outputs n = tid*4 .. tid*4+3 for all 16 rows.
  const int n4 = tid << 2;
  float w1r[4][8];
#pragma unroll
  for (int jr = 0; jr < 4; ++jr) {
    float4 wa = *(const float4*)(W1 + (long)(n4 + jr) * 8);
    float4 wb = *(const float4*)(W1 + (long)(n4 + jr) * 8 + 4);
    w1r[jr][0] = wa.x; w1r[jr][1] = wa.y; w1r[jr][2] = wa.z; w1r[jr][3] = wa.w;
    w1r[jr][4] = wb.x; w1r[jr][5] = wb.y; w1r[jr][6] = wb.z; w1r[jr][7] = wb.w;
  }
  float4 bb = *(const float4*)(b1 + n4);
  const float b1a[4] = {bb.x, bb.y, bb.z, bb.w};
  const float gv = *gateF;
#pragma unroll 2
  for (int r = 0; r < 16; ++r) {
    float qm8[8];
#pragma unroll
    for (int k = 0; k < 8; ++k) qm8[k] = qmL[r * 8 + k];   // LDS broadcast
    union { unsigned short u16[4]; ushort4 v; } pk;
#pragma unroll
    for (int jr = 0; jr < 4; ++jr) {
      float a = b1a[jr];
#pragma unroll
      for (int k = 0; k < 8; ++k) a += qm8[k] * w1r[jr][k];
      pk.u16[jr] = f2bf_bits(fmaxf(a, 0.0f));
    }
    *(ushort4*)(hq + (m0 + r) * 2048 + n4) = pk.v;
    if (gv != 1.0f) {
      float xs8[8];
#pragma unroll
      for (int k = 0; k < 8; ++k) xs8[k] = xsL[r * 8 + k];
#pragma unroll
      for (int jr = 0; jr < 4; ++jr) {
        float a = b1a[jr];
#pragma unroll
        for (int k = 0; k < 8; ++k) a += xs8[k] * w1r[jr][k];
        pk.u16[jr] = f2bf_bits(fmaxf(a, 0.0f));
      }
      *(ushort4*)(hc + (m0 + r) * 2048 + n4) = pk.v;
    }
  }
}

// ---------------------------------------------------------------------------
// FFN-out (R14 form): grid (64, 8, 2) x 128 threads (2-wave K-split).
// z=0: Fb = hq@W2^T+b2 (bf16). z=1 (cond gateF!=1): Fc = hc@W2^T+b2.
// ---------------------------------------------------------------------------
__global__ __launch_bounds__(128) void gemm_ffnout(
    const __hip_bfloat16* __restrict__ hq,
    const __hip_bfloat16* __restrict__ hc,
    const __hip_bfloat16* __restrict__ W2, const float* __restrict__ b2,
    __hip_bfloat16* __restrict__ Fb, __hip_bfloat16* __restrict__ Fc,
    const float* __restrict__ gateF)
{
  const int z = blockIdx.z;
  if (z == 1 && *gateF == 1.0f) return;
  const __hip_bfloat16* A = z ? hc : hq;
  __hip_bfloat16* C = z ? Fc : Fb;
  __shared__ __align__(16) __hip_bfloat16 sh[32768];   // 64 KB: 2 x ring-2
  const int tid = threadIdx.x;
  const int wid = tid >> 6;
  const int lane = tid & 63;
  const long m0 = (long)blockIdx.x * 64;
  const long n0 = (long)blockIdx.y * 64;
  floatx4 acc[4][4];
#pragma unroll
  for (int i = 0; i < 4; ++i)
#pragma unroll
    for (int j = 0; j < 4; ++j) acc[i][j] = (floatx4){0.f, 0.f, 0.f, 0.f};
  gemm_core_ks(A, W2, 2048, wid * 1024, 16, m0, n0, lane, sh + wid * 16384, acc);
  if (!ks_reduce(acc, sh, wid, lane)) return;   // wave0 continues
  store_bf16(acc, C, b2, m0, n0, lane);
}

// ---------------------------------------------------------------------------
// input prep: fp32->bf16 for x, Wq, Wo, W2; conditional Wk/Wv.
// (W1 stays fp32 — consumed directly by wo_lnffn.)
// ---------------------------------------------------------------------------
__device__ __forceinline__ void cvt_one(const float* s, __hip_bfloat16* d, int n,
                                        long tid, long stride) {
  const int n4 = n >> 2;
  for (long i = tid; i < n4; i += stride) {
    float4 v = ((const float4*)s)[i];
    ushort4 u;
    u.x = f2bf_bits(v.x); u.y = f2bf_bits(v.y);
    u.z = f2bf_bits(v.z); u.w = f2bf_bits(v.w);
    ((ushort4*)d)[i] = u;
  }
}

__global__ __launch_bounds__(256) void prep_inputs(
    const float* x, __hip_bfloat16* x_bf,
    const float* Wq, __hip_bfloat16* Wq_bf,
    const float* Wo, __hip_bfloat16* Wo_bf,
    const float* W2, __hip_bfloat16* W2_bf,
    const float* Wk, __hip_bfloat16* Wk_bf,
    const float* Wv, __hip_bfloat16* Wv_bf,
    const float* gateA)
{
  const long stride = (long)gridDim.x * blockDim.x;
  const long tid = (long)blockIdx.x * blockDim.x + threadIdx.x;
  cvt_one(x, x_bf, 4096 * 512, tid, stride);
  cvt_one(Wq, Wq_bf, 512 * 512, tid, stride);
  cvt_one(Wo, Wo_bf, 512 * 512, tid, stride);
  cvt_one(W2, W2_bf, 512 * 2048, tid, stride);
  if (*gateA != 1.0f) {
    cvt_one(Wk, Wk_bf, 512 * 512, tid, stride);
    cvt_one(Wv, Wv_bf, 512 * 512, tid, stride);
  }
}

// ---------------------------------------------------------------------------
// Final LN: out = LN(x1 + mix(Fb, Fc; gateF)), Fb/Fc bf16 (R12).
// Wave-per-row, 4 rows/block, no barriers. grid 1024.
// ---------------------------------------------------------------------------
__global__ __launch_bounds__(256) void add_ln3(
    const float* __restrict__ x1, const __hip_bfloat16* __restrict__ Fb,
    const __hip_bfloat16* __restrict__ Fc, const float* __restrict__ gateF,
    const float* __restrict__ lw, const float* __restrict__ lb,
    float* __restrict__ out)
{
  const int tid = threadIdx.x;
  const int wv = tid >> 6, lane = tid & 63;
  const int row = blockIdx.x * 4 + wv;
  const long base = (long)row * 512;
  const int c0 = lane * 8;
  float4 a0 = *(const float4*)(x1 + base + c0);
  float4 a1 = *(const float4*)(x1 + base + c0 + 4);
  union { unsigned short u16[8]; uint4 v; } fb;
  fb.v = *(const uint4*)(Fb + base + c0);
  const float xa[8] = {a0.x, a0.y, a0.z, a0.w, a1.x, a1.y, a1.z, a1.w};
  float s[8];
  const float gv = *gateF;
  if (gv != 1.0f) {
    union { unsigned short u16[8]; uint4 v; } fc;
    fc.v = *(const uint4*)(Fc + base + c0);
    const float om = 1.0f - gv;
#pragma unroll
    for (int i = 0; i < 8; ++i)
      s[i] = xa[i] + gv * bfbits2f(fb.u16[i]) + om * bfbits2f(fc.u16[i]);
  } else {
#pragma unroll
    for (int i = 0; i < 8; ++i) s[i] = xa[i] + bfbits2f(fb.u16[i]);
  }
  float sum = 0.f, ssq = 0.f;
#pragma unroll
  for (int i = 0; i < 8; ++i) { sum += s[i]; ssq += s[i] * s[i]; }
#pragma unroll
  for (int off = 32; off > 0; off >>= 1) {
    sum += __shfl_xor(sum, off);
    ssq += __shfl_xor(ssq, off);
  }
  const float mean = sum * (1.0f / 512.0f);
  const float var = ssq * (1.0f / 512.0f) - mean * mean;
  const float rstd = rsqrtf(fmaxf(var, 0.0f) + 1e-5f);
  float4 w0 = *(const float4*)(lw + c0);
  float4 w1 = *(const float4*)(lw + c0 + 4);
  float4 g0 = *(const float4*)(lb + c0);
  float4 g1 = *(const float4*)(lb + c0 + 4);
  const float wf[8] = {w0.x, w0.y, w0.z, w0.w, w1.x, w1.y, w1.z, w1.w};
  const float gf8[8] = {g0.x, g0.y, g0.z, g0.w, g1.x, g1.y, g1.z, g1.w};
  float o[8];
#pragma unroll
  for (int i = 0; i < 8; ++i) o[i] = (s[i] - mean) * rstd * wf[i] + gf8[i];
  *(float4*)(out + base + c0) = (float4){o[0], o[1], o[2], o[3]};
  *(float4*)(out + base + c0 + 4) = (float4){o[4], o[5], o[6], o[7]};
}

// ---------------------------------------------------------------------------
extern "C" void kernel_launch(void* const* d_in, const int* in_sizes, int n_in,
                              void* d_out, int out_size, void* d_ws, size_t ws_size,
                              hipStream_t stream) {
  const float* x     = (const float*)d_in[0];
  const float* Wq    = (const float*)d_in[1];
  const float* bq    = (const float*)d_in[2];
  const float* Wk    = (const float*)d_in[3];
  const float* bk    = (const float*)d_in[4];
  const float* Wv    = (const float*)d_in[5];
  const float* bv    = (const float*)d_in[6];
  const float* theta = (const float*)d_in[7];
  const float* gateA = (const float*)d_in[8];
  const float* Wo    = (const float*)d_in[9];
  const float* bo    = (const float*)d_in[10];
  const float* ln1w  = (const float*)d_in[11];
  const float* ln1b  = (const float*)d_in[12];
  const float* W1    = (const float*)d_in[13];
  const float* b1    = (const float*)d_in[14];
  const float* W2    = (const float*)d_in[15];
  const float* b2    = (const float*)d_in[16];
  const float* phi   = (const float*)d_in[17];
  const float* gateF = (const float*)d_in[18];
  const float* ln2w  = (const float*)d_in[19];
  const float* ln2b  = (const float*)d_in[20];
  float* out = (float*)d_out;

  const size_t MB = 1024 * 1024;
  char* wsb = (char*)d_ws;
  __hip_bfloat16* x_bf    = (__hip_bfloat16*)(wsb + 0 * MB);            // 4 MB
  __hip_bfloat16* Wq_bf   = (__hip_bfloat16*)(wsb + 4 * MB);            // 0.5 MB
  __hip_bfloat16* Wo_bf   = (__hip_bfloat16*)(wsb + 4 * MB + 512 * 1024);
  __hip_bfloat16* W2_bf   = (__hip_bfloat16*)(wsb + 5 * MB);            // 2 MB
  __hip_bfloat16* mix_bf  = (__hip_bfloat16*)(wsb + 8 * MB);            // 4 MB
  float*          x1      = (float*)(wsb + 16 * MB);                    // 8 MB
  __hip_bfloat16* hq_bf   = (__hip_bfloat16*)(wsb + 24 * MB);           // 16 MB
  __hip_bfloat16* Fb_bf   = (__hip_bfloat16*)(wsb + 40 * MB);           // 4 MB
  // conditional (gate != 1) buffers
  float*          Qb      = (float*)(wsb + 52 * MB);                    // 8 MB
  __hip_bfloat16* Wk_bf   = (__hip_bfloat16*)(wsb + 60 * MB);
  __hip_bfloat16* Wv_bf   = (__hip_bfloat16*)(wsb + 60 * MB + 512 * 1024);
  float*          Kb2     = (float*)(wsb + 61 * MB);                    // 8 MB
  float*          Vb2     = (float*)(wsb + 69 * MB);                    // 8 MB
  __hip_bfloat16* hc_bf   = (__hip_bfloat16*)(wsb + 77 * MB);           // 16 MB
  __hip_bfloat16* Fc_bf   = (__hip_bfloat16*)(wsb + 93 * MB);           // 4 MB

  // 1. input prep (all conversions; W1 stays fp32)
  prep_inputs<<<1024, 256, 0, stream>>>(
      x, x_bf, Wq, Wq_bf, Wo, Wo_bf, W2, W2_bf, Wk, Wk_bf, Wv, Wv_bf, gateA);
  // 2. QKV (R14): z=0 Q+quantum -> mix_bf (+Qb cond); z=1/2 K/V (cond)
  gemm_qkv<<<dim3(64, 8, 3), 128, 0, stream>>>(
      x_bf, Wq_bf, Wk_bf, Wv_bf, bq, bk, bv,
      mix_bf, Qb, Kb2, Vb2, theta, gateA);
  // 3. R19 fused: [cond blend] ; attn = mix@Wo^T+bo ; x1 = LN1(x+attn) ;
  //    hq (+hc cond). attn_blend dispatch ELIMINATED.
  wo_lnffn<<<256, 512, 0, stream>>>(
      mix_bf, Wo_bf, bo, x, ln1w, ln1b, x1, phi, W1, b1, hq_bf, hc_bf, gateF,
      mix_bf, Qb, Kb2, Vb2, gateA);
  // 4. Fb = hq @ W2^T + b2 (z=0); Fc = hc @ W2^T + b2 (z=1, cond), bf16
  gemm_ffnout<<<dim3(64, 8, 2), 128, 0, stream>>>(
      hq_bf, hc_bf, W2_bf, b2, Fb_bf, Fc_bf, gateF);
  // 5. out = LN(x1 + gF*Fb + (1-gF)*Fc)
  add_ln3<<<1024, 256, 0, stream>>>(x1, Fb_bf, Fc_bf, gateF, ln2w, ln2b, out);
}